// Round 1
// baseline (2400.809 us; speedup 1.0000x reference)
//
#include <hip/hip_runtime.h>
#include <cmath>

#define BB   2
#define LL   2048
#define DM   512
#define DI   1024
#define DS   32
#define DTR  64
#define NT   (BB*LL)   // 4096 tokens

__device__ __forceinline__ float sigmoidf_(float x){ return 1.f/(1.f+__expf(-x)); }
__device__ __forceinline__ float siluf_(float x){ return x*sigmoidf_(x); }

// block-wide sum over 256 threads (4 waves)
__device__ __forceinline__ float block_sum4(float v, float* red) {
  #pragma unroll
  for (int off = 32; off >= 1; off >>= 1) v += __shfl_xor(v, off, 64);
  int w = threadIdx.x >> 6;
  __syncthreads();
  if ((threadIdx.x & 63) == 0) red[w] = v;
  __syncthreads();
  return red[0] + red[1] + red[2] + red[3];
}

// -------- fused dwconv(k=3, chan-mult 2) + silu + LN over 1024 --------
__global__ __launch_bounds__(256) void conv_ln_k(
    const float* __restrict__ x, const float* __restrict__ cw, const float* __restrict__ cb,
    const float* __restrict__ g, const float* __restrict__ bt, float* __restrict__ xc)
{
  int token = blockIdx.x;
  int l = token & (LL-1);
  __shared__ float red[4];
  float v[4]; float sum = 0.f;
  #pragma unroll
  for (int i = 0; i < 4; i++) {
    int o = threadIdx.x + i*256;
    int c = o >> 1;
    const float* xp = x + (long)token*DM + c;
    float s = cb[o];
    if (l >= 1)    s += xp[-DM] * cw[o*3+0];
                   s += xp[0]   * cw[o*3+1];
    if (l < LL-1)  s += xp[DM]  * cw[o*3+2];
    float t = siluf_(s);
    v[i] = t; sum += t;
  }
  float mean = block_sum4(sum, red) * (1.f/DI);
  float vs = 0.f;
  #pragma unroll
  for (int i = 0; i < 4; i++) { float d = v[i]-mean; vs += d*d; }
  float var = block_sum4(vs, red) * (1.f/DI);
  float inv = rsqrtf(var + 1e-5f);
  #pragma unroll
  for (int i = 0; i < 4; i++) {
    int o = threadIdx.x + i*256;
    xc[(long)token*DI + o] = (v[i]-mean)*inv*g[o] + bt[o];
  }
}

// -------- generic f32 GEMM: C(M,N) = act(A(M,K,lda) @ W(K,N) + bias) --------
// act: 0=none, 1=sigmoid, 2=softplus, 3=bias-only
__global__ __launch_bounds__(256) void gemm_k(
    const float* __restrict__ A, int lda,
    const float* __restrict__ W,
    const float* __restrict__ bias,
    float* __restrict__ C,
    int M, int N, int K, int act)
{
  __shared__ float As[16][64 + 1];
  __shared__ float Ws[16][64];
  int tid = threadIdx.x;
  int tx = tid & 15;   // n dir
  int ty = tid >> 4;   // m dir
  int m0 = blockIdx.y * 64;
  int n0 = blockIdx.x * 64;
  float acc[4][4] = {};
  for (int k0 = 0; k0 < K; k0 += 16) {
    #pragma unroll
    for (int i = 0; i < 4; i++) {
      int idx = tid + i*256;
      int m = idx >> 4, kk = idx & 15;
      As[kk][m] = A[(long)(m0+m)*lda + k0 + kk];
    }
    #pragma unroll
    for (int i = 0; i < 4; i++) {
      int idx = tid + i*256;
      int kk = idx >> 6, n = idx & 63;
      Ws[kk][n] = W[(long)(k0+kk)*N + n0 + n];
    }
    __syncthreads();
    #pragma unroll
    for (int kk = 0; kk < 16; kk++) {
      float a[4], w[4];
      #pragma unroll
      for (int i = 0; i < 4; i++) a[i] = As[kk][ty*4+i];
      #pragma unroll
      for (int j = 0; j < 4; j++) w[j] = Ws[kk][tx*4+j];
      #pragma unroll
      for (int i = 0; i < 4; i++)
        #pragma unroll
        for (int j = 0; j < 4; j++)
          acc[i][j] = fmaf(a[i], w[j], acc[i][j]);
    }
    __syncthreads();
  }
  #pragma unroll
  for (int i = 0; i < 4; i++) {
    int m = m0 + ty*4 + i;
    #pragma unroll
    for (int j = 0; j < 4; j++) {
      int n = n0 + tx*4 + j;
      float v = acc[i][j];
      if (bias) v += bias[n];
      if (act == 1) v = sigmoidf_(v);
      else if (act == 2) v = fmaxf(v, 0.f) + log1pf(__expf(-fabsf(v)));
      C[(long)m*N + n] = v;
    }
  }
}

// -------- causal dwconv(k=4) + silu over xs = xz[..., :1024] --------
__global__ __launch_bounds__(256) void ssm_conv_k(
    const float* __restrict__ xz, const float* __restrict__ w,
    const float* __restrict__ bias, float* __restrict__ xs)
{
  long i = (long)blockIdx.x*256 + threadIdx.x;   // over NT*DI
  int d = (int)(i & (DI-1));
  long tok = i >> 10;
  int l = (int)(tok & (LL-1));
  const float* base = xz + (tok - l) * (2*DI) + d;
  float s = bias[d];
  #pragma unroll
  for (int k = 0; k < 4; k++) {
    int ll = l + k - 3;
    if (ll >= 0) s = fmaf(base[(long)ll*2*DI], w[d*4+k], s);
  }
  xs[i] = siluf_(s);
}

// -------- selective scan: one channel per 32-lane half-wave --------
__global__ __launch_bounds__(256) void scan_k(
  const float* __restrict__ delta, const float* __restrict__ xs,
  const float* __restrict__ xz, const float* __restrict__ dbl,
  const float* __restrict__ A_log, const float* __restrict__ Dp,
  float* __restrict__ yg)
{
  int gtid = blockIdx.x*256 + threadIdx.x;
  int n = gtid & (DS-1);
  int ch = gtid >> 5;             // b*DI + d
  int b = ch >> 10, d = ch & (DI-1);
  float A = -__expf(A_log[d*DS + n]);
  float D = Dp[d];
  float h = 0.f;
  const float* dl = delta + (long)b*LL*DI + d;
  const float* up = xs    + (long)b*LL*DI + d;
  const float* zp = xz    + (long)b*LL*2*DI + DI + d;
  const float* Bp = dbl   + (long)b*LL*128 + DTR + n;
  const float* Cp = Bp + DS;
  float* yp = yg + (long)b*LL*DI + d;
  for (int t = 0; t < LL; t++) {
    float dt = dl[(long)t*DI];
    float u  = up[(long)t*DI];
    float Bt = Bp[(long)t*128];
    float Ct = Cp[(long)t*128];
    float dA = __expf(dt*A);
    h = fmaf(dA, h, dt*u*Bt);
    float y = h*Ct;
    #pragma unroll
    for (int off = 16; off >= 1; off >>= 1) y += __shfl_xor(y, off, 64);
    if (n == 0) {
      float z = zp[(long)t*2*DI];
      yp[(long)t*DI] = (y + u*D) * siluf_(z);
    }
  }
}

// -------- combined = ssm*silu(ge) + xc*(1-gate) --------
__global__ __launch_bounds__(256) void combine_k(
    const float* __restrict__ ssm, const float* __restrict__ gate,
    const float* __restrict__ xc, float* __restrict__ comb)
{
  long i = (long)blockIdx.x*256 + threadIdx.x;  // over NT*DI
  int o = (int)(i & (DI-1));
  long tok = i >> 10;
  float gv = gate[tok*DM + (o>>1)];
  comb[i] = ssm[i] * siluf_(gv) + xc[i] * (1.f - gv);
}

// -------- final LN over 512 of (pre + residual) --------
__global__ __launch_bounds__(256) void final_ln_k(
    const float* __restrict__ pre, const float* __restrict__ x,
    const float* __restrict__ g, const float* __restrict__ bt, float* __restrict__ out)
{
  int token = blockIdx.x;
  __shared__ float red[4];
  float v[2]; float sum = 0.f;
  #pragma unroll
  for (int i = 0; i < 2; i++) {
    int o = threadIdx.x + i*256;
    float t = pre[(long)token*DM+o] + x[(long)token*DM+o];
    v[i] = t; sum += t;
  }
  float mean = block_sum4(sum, red) * (1.f/DM);
  float vs = 0.f;
  #pragma unroll
  for (int i = 0; i < 2; i++) { float d = v[i]-mean; vs += d*d; }
  float var = block_sum4(vs, red) * (1.f/DM);
  float inv = rsqrtf(var + 1e-5f);
  #pragma unroll
  for (int i = 0; i < 2; i++) {
    int o = threadIdx.x + i*256;
    out[(long)token*DM + o] = (v[i]-mean)*inv*g[o] + bt[o];
  }
}

extern "C" void kernel_launch(void* const* d_in, const int* in_sizes, int n_in,
                              void* d_out, int out_size, void* d_ws, size_t ws_size,
                              hipStream_t stream)
{
  const float* x         = (const float*)d_in[0];
  const float* conv_w    = (const float*)d_in[1];
  const float* conv_b    = (const float*)d_in[2];
  const float* gate_w    = (const float*)d_in[3];
  const float* gate_b    = (const float*)d_in[4];
  const float* out_w     = (const float*)d_in[5];
  const float* out_b     = (const float*)d_in[6];
  const float* ln1_g     = (const float*)d_in[7];
  const float* ln1_b     = (const float*)d_in[8];
  const float* ln2_g     = (const float*)d_in[9];
  const float* ln2_b     = (const float*)d_in[10];
  const float* in_proj_w = (const float*)d_in[11];
  const float* ssm_conv_w= (const float*)d_in[12];
  const float* ssm_conv_b= (const float*)d_in[13];
  const float* x_proj_w  = (const float*)d_in[14];
  const float* dt_proj_w = (const float*)d_in[15];
  const float* dt_proj_b = (const float*)d_in[16];
  const float* A_log     = (const float*)d_in[17];
  const float* D_param   = (const float*)d_in[18];
  const float* out_proj_w= (const float*)d_in[19];

  float* ws   = (float*)d_ws;
  float* xz    = ws;                          // NT*2*DI
  float* xc    = xz + (long)NT*2*DI;          // NT*DI
  float* gate  = xc + (long)NT*DI;            // NT*DM
  float* xs    = gate + (long)NT*DM;          // NT*DI
  float* dbl   = xs + (long)NT*DI;            // NT*128
  float* delta = dbl + (long)NT*128;          // NT*DI
  float* yg    = delta + (long)NT*DI;         // NT*DI
  float* ssm   = delta;   // reuse (delta dead after scan)
  float* comb  = xs;      // reuse (xs dead after scan)
  float* pre   = yg;      // reuse (yg dead after out_proj)
  float* outp  = (float*)d_out;

  conv_ln_k<<<NT, 256, 0, stream>>>(x, conv_w, conv_b, ln2_g, ln2_b, xc);
  gemm_k<<<dim3(DM/64, NT/64), 256, 0, stream>>>(x, DM, gate_w, gate_b, gate, NT, DM, DM, 1);
  gemm_k<<<dim3(2*DI/64, NT/64), 256, 0, stream>>>(xc, DI, in_proj_w, nullptr, xz, NT, 2*DI, DI, 0);
  ssm_conv_k<<<(NT*DI)/256, 256, 0, stream>>>(xz, ssm_conv_w, ssm_conv_b, xs);
  gemm_k<<<dim3(128/64, NT/64), 256, 0, stream>>>(xs, DI, x_proj_w, nullptr, dbl, NT, 128, DI, 0);
  gemm_k<<<dim3(DI/64, NT/64), 256, 0, stream>>>(dbl, 128, dt_proj_w, dt_proj_b, delta, NT, DI, DTR, 2);
  scan_k<<<(BB*DI*DS)/256, 256, 0, stream>>>(delta, xs, xz, dbl, A_log, D_param, yg);
  gemm_k<<<dim3(DI/64, NT/64), 256, 0, stream>>>(yg, DI, out_proj_w, nullptr, ssm, NT, DI, DI, 0);
  combine_k<<<(NT*DI)/256, 256, 0, stream>>>(ssm, gate, xc, comb);
  gemm_k<<<dim3(DM/64, NT/64), 256, 0, stream>>>(comb, DI, out_w, out_b, pre, NT, DM, DI, 3);
  final_ln_k<<<NT, 256, 0, stream>>>(pre, x, ln1_g, ln1_b, outp);
}

// Round 2
// 1012.887 us; speedup vs baseline: 2.3703x; 2.3703x over previous
//
#include <hip/hip_runtime.h>
#include <cmath>

#define BB   2
#define LL   2048
#define DM   512
#define DI   1024
#define DS   32
#define DTR  64
#define NT   (BB*LL)   // 4096 tokens

__device__ __forceinline__ float sigmoidf_(float x){ return 1.f/(1.f+__expf(-x)); }
__device__ __forceinline__ float siluf_(float x){ return x*sigmoidf_(x); }

// block-wide sum over 256 threads (4 waves)
__device__ __forceinline__ float block_sum4(float v, float* red) {
  #pragma unroll
  for (int off = 32; off >= 1; off >>= 1) v += __shfl_xor(v, off, 64);
  int w = threadIdx.x >> 6;
  __syncthreads();
  if ((threadIdx.x & 63) == 0) red[w] = v;
  __syncthreads();
  return red[0] + red[1] + red[2] + red[3];
}

// -------- fused dwconv(k=3, chan-mult 2) + silu + LN over 1024 --------
__global__ __launch_bounds__(256) void conv_ln_k(
    const float* __restrict__ x, const float* __restrict__ cw, const float* __restrict__ cb,
    const float* __restrict__ g, const float* __restrict__ bt, float* __restrict__ xc)
{
  int token = blockIdx.x;
  int l = token & (LL-1);
  __shared__ float red[4];
  float v[4]; float sum = 0.f;
  #pragma unroll
  for (int i = 0; i < 4; i++) {
    int o = threadIdx.x + i*256;
    int c = o >> 1;
    const float* xp = x + (long)token*DM + c;
    float s = cb[o];
    if (l >= 1)    s += xp[-DM] * cw[o*3+0];
                   s += xp[0]   * cw[o*3+1];
    if (l < LL-1)  s += xp[DM]  * cw[o*3+2];
    float t = siluf_(s);
    v[i] = t; sum += t;
  }
  float mean = block_sum4(sum, red) * (1.f/DI);
  float vs = 0.f;
  #pragma unroll
  for (int i = 0; i < 4; i++) { float d = v[i]-mean; vs += d*d; }
  float var = block_sum4(vs, red) * (1.f/DI);
  float inv = rsqrtf(var + 1e-5f);
  #pragma unroll
  for (int i = 0; i < 4; i++) {
    int o = threadIdx.x + i*256;
    xc[(long)token*DI + o] = (v[i]-mean)*inv*g[o] + bt[o];
  }
}

// -------- generic f32 GEMM: C(M,N) = act(A(M,K,lda) @ W(K,N) + bias) --------
// mode: 0=none, 1=sigmoid, 2=softplus->storeT pair (C=softplusT, C2=(softplus*U)T), 3=bias-only
__global__ __launch_bounds__(256) void gemm_k(
    const float* __restrict__ A, int lda,
    const float* __restrict__ W,
    const float* __restrict__ bias,
    float* __restrict__ C,
    float* __restrict__ C2,
    const float* __restrict__ U,
    int M, int N, int K, int mode)
{
  __shared__ float As[16][64 + 1];
  __shared__ float Ws[16][64];
  int tid = threadIdx.x;
  int tx = tid & 15;   // n dir
  int ty = tid >> 4;   // m dir
  int m0 = blockIdx.y * 64;
  int n0 = blockIdx.x * 64;
  float acc[4][4] = {};
  for (int k0 = 0; k0 < K; k0 += 16) {
    #pragma unroll
    for (int i = 0; i < 4; i++) {
      int idx = tid + i*256;
      int m = idx >> 4, kk = idx & 15;
      As[kk][m] = A[(long)(m0+m)*lda + k0 + kk];
    }
    #pragma unroll
    for (int i = 0; i < 4; i++) {
      int idx = tid + i*256;
      int kk = idx >> 6, n = idx & 63;
      Ws[kk][n] = W[(long)(k0+kk)*N + n0 + n];
    }
    __syncthreads();
    #pragma unroll
    for (int kk = 0; kk < 16; kk++) {
      float a[4], w[4];
      #pragma unroll
      for (int i = 0; i < 4; i++) a[i] = As[kk][ty*4+i];
      #pragma unroll
      for (int j = 0; j < 4; j++) w[j] = Ws[kk][tx*4+j];
      #pragma unroll
      for (int i = 0; i < 4; i++)
        #pragma unroll
        for (int j = 0; j < 4; j++)
          acc[i][j] = fmaf(a[i], w[j], acc[i][j]);
    }
    __syncthreads();
  }
  #pragma unroll
  for (int i = 0; i < 4; i++) {
    int m = m0 + ty*4 + i;
    #pragma unroll
    for (int j = 0; j < 4; j++) {
      int n = n0 + tx*4 + j;
      float v = acc[i][j];
      if (bias) v += bias[n];
      if (mode == 1) v = sigmoidf_(v);
      else if (mode == 2) {
        v = fmaxf(v, 0.f) + log1pf(__expf(-fabsf(v)));
        C[(long)n*M + m]  = v;                        // deltaT [d][token]
        C2[(long)n*M + m] = v * U[(long)m*N + n];     // dtuT   [d][token]
        continue;
      }
      C[(long)m*N + n] = v;
    }
  }
}

// -------- causal dwconv(k=4) + silu over xs = xz[..., :1024] --------
__global__ __launch_bounds__(256) void ssm_conv_k(
    const float* __restrict__ xz, const float* __restrict__ w,
    const float* __restrict__ bias, float* __restrict__ xs)
{
  long i = (long)blockIdx.x*256 + threadIdx.x;   // over NT*DI
  int d = (int)(i & (DI-1));
  long tok = i >> 10;
  int l = (int)(tok & (LL-1));
  const float* base = xz + (tok - l) * (2*DI) + d;
  float s = bias[d];
  #pragma unroll
  for (int k = 0; k < 4; k++) {
    int ll = l + k - 3;
    if (ll >= 0) s = fmaf(base[(long)ll*2*DI], w[d*4+k], s);
  }
  xs[i] = siluf_(s);
}

// -------- selective scan: 1 wave = 2 channels, t in chunks of 32 --------
// reads dtT/dtuT [d][b*LL+t] (coalesced), dbl B/C rows (coalesced),
// writes ygT [d][b*LL+t] (coalesced). y = sum_n h*C via LDS 32x32 transpose.
__global__ __launch_bounds__(64) void scan_k(
  const float* __restrict__ dtT, const float* __restrict__ dtuT,
  const float* __restrict__ dbl, const float* __restrict__ A_log,
  float* __restrict__ ygT)
{
  __shared__ float ys[2*32*36];
  int lane = threadIdx.x;        // 0..63
  int half = lane >> 5;
  int ln = lane & 31;            // n index; also t-slot index in reduce
  int ch = blockIdx.x*2 + half;  // 0..2047 = b*DI+d
  int b = ch >> 10, d = ch & (DI-1);
  float An = -__expf(A_log[d*DS + ln]);
  const float* dtp  = dtT  + (long)d*NT + (long)b*LL;
  const float* dtup = dtuT + (long)d*NT + (long)b*LL;
  const float* blp  = dbl + (long)b*LL*128 + DTR + ln;
  float* yp = ygT + (long)d*NT + (long)b*LL;
  float* lds = ys + half*(32*36);
  float h = 0.f;
  for (int c = 0; c < 64; c++) {
    int t0 = c*32;
    float dtv  = dtp[t0 + ln];    // 32 consecutive timesteps, coalesced
    float dtuv = dtup[t0 + ln];
    float Bv[32], Cv[32];
    #pragma unroll
    for (int tt = 0; tt < 32; tt++) {
      Bv[tt] = blp[(long)(t0+tt)*128];
      Cv[tt] = blp[(long)(t0+tt)*128 + DS];
    }
    float av[32], wv[32];
    #pragma unroll
    for (int tt = 0; tt < 32; tt++) {
      float dt_t  = __shfl(dtv,  tt, 32);
      float dtu_t = __shfl(dtuv, tt, 32);
      av[tt] = __expf(dt_t * An);
      wv[tt] = dtu_t * Bv[tt];
    }
    #pragma unroll
    for (int tt = 0; tt < 32; tt++) {
      h = fmaf(av[tt], h, wv[tt]);
      lds[tt*36 + ln] = h * Cv[tt];
    }
    __syncthreads();
    float y = 0.f;
    #pragma unroll
    for (int k = 0; k < 8; k++) {
      int kk = (k + (ln & 7)) & 7;   // stagger to spread LDS banks
      const float4 v4 = *reinterpret_cast<const float4*>(&lds[ln*36 + kk*4]);
      y += v4.x + v4.y + v4.z + v4.w;
    }
    yp[t0 + ln] = y;
    __syncthreads();
  }
}

// -------- yg[t][d] = (ygT[d][t] + xs*D) * silu(z) ; tiled transpose --------
__global__ __launch_bounds__(256) void mulz_k(
    const float* __restrict__ ygT, const float* __restrict__ xs,
    const float* __restrict__ xz, const float* __restrict__ Dp,
    float* __restrict__ yg)
{
  __shared__ float tile[32][33];
  int d0 = blockIdx.x*32, t0 = blockIdx.y*32;
  int tx = threadIdx.x, ty = threadIdx.y;   // 32, 8
  #pragma unroll
  for (int k = 0; k < 4; k++)
    tile[ty+8*k][tx] = ygT[(long)(d0+ty+8*k)*NT + t0+tx];
  __syncthreads();
  #pragma unroll
  for (int k = 0; k < 4; k++) {
    int tok = t0+ty+8*k; int d = d0+tx;
    float u = xs[(long)tok*DI + d];
    float z = xz[(long)tok*2*DI + DI + d];
    yg[(long)tok*DI + d] = (tile[tx][ty+8*k] + u*Dp[d]) * siluf_(z);
  }
}

// -------- combined = ssm*silu(ge) + xc*(1-gate) --------
__global__ __launch_bounds__(256) void combine_k(
    const float* __restrict__ ssm, const float* __restrict__ gate,
    const float* __restrict__ xc, float* __restrict__ comb)
{
  long i = (long)blockIdx.x*256 + threadIdx.x;  // over NT*DI
  int o = (int)(i & (DI-1));
  long tok = i >> 10;
  float gv = gate[tok*DM + (o>>1)];
  comb[i] = ssm[i] * siluf_(gv) + xc[i] * (1.f - gv);
}

// -------- final LN over 512 of (pre + residual) --------
__global__ __launch_bounds__(256) void final_ln_k(
    const float* __restrict__ pre, const float* __restrict__ x,
    const float* __restrict__ g, const float* __restrict__ bt, float* __restrict__ out)
{
  int token = blockIdx.x;
  __shared__ float red[4];
  float v[2]; float sum = 0.f;
  #pragma unroll
  for (int i = 0; i < 2; i++) {
    int o = threadIdx.x + i*256;
    float t = pre[(long)token*DM+o] + x[(long)token*DM+o];
    v[i] = t; sum += t;
  }
  float mean = block_sum4(sum, red) * (1.f/DM);
  float vs = 0.f;
  #pragma unroll
  for (int i = 0; i < 2; i++) { float d = v[i]-mean; vs += d*d; }
  float var = block_sum4(vs, red) * (1.f/DM);
  float inv = rsqrtf(var + 1e-5f);
  #pragma unroll
  for (int i = 0; i < 2; i++) {
    int o = threadIdx.x + i*256;
    out[(long)token*DM + o] = (v[i]-mean)*inv*g[o] + bt[o];
  }
}

extern "C" void kernel_launch(void* const* d_in, const int* in_sizes, int n_in,
                              void* d_out, int out_size, void* d_ws, size_t ws_size,
                              hipStream_t stream)
{
  const float* x         = (const float*)d_in[0];
  const float* conv_w    = (const float*)d_in[1];
  const float* conv_b    = (const float*)d_in[2];
  const float* gate_w    = (const float*)d_in[3];
  const float* gate_b    = (const float*)d_in[4];
  const float* out_w     = (const float*)d_in[5];
  const float* out_b     = (const float*)d_in[6];
  const float* ln1_g     = (const float*)d_in[7];
  const float* ln1_b     = (const float*)d_in[8];
  const float* ln2_g     = (const float*)d_in[9];
  const float* ln2_b     = (const float*)d_in[10];
  const float* in_proj_w = (const float*)d_in[11];
  const float* ssm_conv_w= (const float*)d_in[12];
  const float* ssm_conv_b= (const float*)d_in[13];
  const float* x_proj_w  = (const float*)d_in[14];
  const float* dt_proj_w = (const float*)d_in[15];
  const float* dt_proj_b = (const float*)d_in[16];
  const float* A_log     = (const float*)d_in[17];
  const float* D_param   = (const float*)d_in[18];
  const float* out_proj_w= (const float*)d_in[19];

  float* ws    = (float*)d_ws;
  float* xz     = ws;                         // NT*2*DI        (8M)
  float* xc     = xz    + (long)NT*2*DI;      // NT*DI          (4M)
  float* gate   = xc    + (long)NT*DI;        // NT*DM          (2M)
  float* xs     = gate  + (long)NT*DM;        // NT*DI          (4M)
  float* dbl    = xs    + (long)NT*DI;        // NT*128         (0.5M)
  float* deltaT = dbl   + (long)NT*128;       // DI*NT          (4M)
  float* dtuT   = deltaT+ (long)NT*DI;        // DI*NT          (4M)
  float* ygT    = dtuT  + (long)NT*DI;        // DI*NT          (4M)
  float* yg     = deltaT;  // reuse (deltaT dead after scan)
  float* ssm    = dtuT;    // reuse (dtuT dead after scan)
  float* comb   = xs;      // reuse (xs dead after mulz)
  float* pre    = ygT;     // reuse (ygT dead after mulz)
  float* outp   = (float*)d_out;

  conv_ln_k<<<NT, 256, 0, stream>>>(x, conv_w, conv_b, ln2_g, ln2_b, xc);
  gemm_k<<<dim3(DM/64, NT/64), 256, 0, stream>>>(x, DM, gate_w, gate_b, gate, nullptr, nullptr, NT, DM, DM, 1);
  gemm_k<<<dim3(2*DI/64, NT/64), 256, 0, stream>>>(xc, DI, in_proj_w, nullptr, xz, nullptr, nullptr, NT, 2*DI, DI, 0);
  ssm_conv_k<<<(NT*DI)/256, 256, 0, stream>>>(xz, ssm_conv_w, ssm_conv_b, xs);
  gemm_k<<<dim3(128/64, NT/64), 256, 0, stream>>>(xs, DI, x_proj_w, nullptr, dbl, nullptr, nullptr, NT, 128, DI, 0);
  gemm_k<<<dim3(DI/64, NT/64), 256, 0, stream>>>(dbl, 128, dt_proj_w, dt_proj_b, deltaT, dtuT, xs, NT, DI, DTR, 2);
  scan_k<<<1024, 64, 0, stream>>>(deltaT, dtuT, dbl, A_log, ygT);
  mulz_k<<<dim3(DI/32, NT/32), dim3(32,8), 0, stream>>>(ygT, xs, xz, D_param, yg);
  gemm_k<<<dim3(DI/64, NT/64), 256, 0, stream>>>(yg, DI, out_proj_w, nullptr, ssm, nullptr, nullptr, NT, DI, DI, 0);
  combine_k<<<(NT*DI)/256, 256, 0, stream>>>(ssm, gate, xc, comb);
  gemm_k<<<dim3(DM/64, NT/64), 256, 0, stream>>>(comb, DI, out_w, out_b, pre, nullptr, nullptr, NT, DM, DI, 3);
  final_ln_k<<<NT, 256, 0, stream>>>(pre, x, ln1_g, ln1_b, outp);
}

// Round 3
// 541.320 us; speedup vs baseline: 4.4351x; 1.8711x over previous
//
#include <hip/hip_runtime.h>
#include <cmath>

#define BB   2
#define LL   2048
#define DM   512
#define DI   1024
#define DS   32
#define DTR  64
#define NT   (BB*LL)   // 4096 tokens

typedef short bf16x8 __attribute__((ext_vector_type(8)));
typedef float f32x4  __attribute__((ext_vector_type(4)));

__device__ __forceinline__ float sigmoidf_(float x){ return 1.f/(1.f+__expf(-x)); }
__device__ __forceinline__ float siluf_(float x){ return x*sigmoidf_(x); }
__device__ __forceinline__ ushort f2b(float f){
  union { float f; unsigned u; } x; x.f = f;
  unsigned r = (x.u + 0x7FFFu + ((x.u >> 16) & 1u)) >> 16;
  return (ushort)r;
}

// block-wide sum over 256 threads (4 waves)
__device__ __forceinline__ float block_sum4(float v, float* red) {
  #pragma unroll
  for (int off = 32; off >= 1; off >>= 1) v += __shfl_xor(v, off, 64);
  int w = threadIdx.x >> 6;
  __syncthreads();
  if ((threadIdx.x & 63) == 0) red[w] = v;
  __syncthreads();
  return red[0] + red[1] + red[2] + red[3];
}

// -------- f32 -> bf16 elementwise (x), 4 elems/thread --------
__global__ __launch_bounds__(256) void convx_k(
    const float* __restrict__ in, ushort* __restrict__ out)
{
  int i = blockIdx.x*256 + threadIdx.x;
  float4 v = reinterpret_cast<const float4*>(in)[i];
  ushort4 o; o.x=f2b(v.x); o.y=f2b(v.y); o.z=f2b(v.z); o.w=f2b(v.w);
  reinterpret_cast<ushort4*>(out)[i] = o;
}

// -------- weight transpose+convert: W[K][N] f32 -> WT[N][K] bf16 --------
__global__ __launch_bounds__(256) void wt_k(
    const float* __restrict__ W, ushort* __restrict__ WT, int K, int N)
{
  __shared__ float t[32][33];
  int n0 = blockIdx.x*32, k0 = blockIdx.y*32;
  int tx = threadIdx.x & 31, ty = threadIdx.x >> 5;  // 32 x 8
  #pragma unroll
  for (int i = 0; i < 4; i++)
    t[ty+8*i][tx] = W[(long)(k0+ty+8*i)*N + n0+tx];
  __syncthreads();
  #pragma unroll
  for (int i = 0; i < 4; i++)
    WT[(long)(n0+ty+8*i)*K + k0+tx] = f2b(t[tx][ty+8*i]);
}

// -------- fused dwconv(k=3, chan-mult 2) + silu + LN over 1024 --------
__global__ __launch_bounds__(256) void conv_ln_k(
    const float* __restrict__ x, const float* __restrict__ cw, const float* __restrict__ cb,
    const float* __restrict__ g, const float* __restrict__ bt,
    float* __restrict__ xc, ushort* __restrict__ xc16)
{
  int token = blockIdx.x;
  int l = token & (LL-1);
  __shared__ float red[4];
  float v[4]; float sum = 0.f;
  #pragma unroll
  for (int i = 0; i < 4; i++) {
    int o = threadIdx.x + i*256;
    int c = o >> 1;
    const float* xp = x + (long)token*DM + c;
    float s = cb[o];
    if (l >= 1)    s += xp[-DM] * cw[o*3+0];
                   s += xp[0]   * cw[o*3+1];
    if (l < LL-1)  s += xp[DM]  * cw[o*3+2];
    float t = siluf_(s);
    v[i] = t; sum += t;
  }
  float mean = block_sum4(sum, red) * (1.f/DI);
  float vs = 0.f;
  #pragma unroll
  for (int i = 0; i < 4; i++) { float d = v[i]-mean; vs += d*d; }
  float var = block_sum4(vs, red) * (1.f/DI);
  float inv = rsqrtf(var + 1e-5f);
  #pragma unroll
  for (int i = 0; i < 4; i++) {
    int o = threadIdx.x + i*256;
    float r = (v[i]-mean)*inv*g[o] + bt[o];
    xc[(long)token*DI + o] = r;
    xc16[(long)token*DI + o] = f2b(r);
  }
}

// -------- bf16 MFMA GEMM: 128x128 tile, BK=32, 4 waves --------
// A: [M][lda] bf16, WT: [N][K] bf16. mode: 0=plain, 1=sigmoid+bias,
// 2=softplus+bias (t-major store), 3=bias, 4=dual f32+bf16
__global__ __launch_bounds__(256) void bgemm_k(
    const ushort* __restrict__ A, int lda,
    const ushort* __restrict__ WT,
    const float* __restrict__ bias,
    float* __restrict__ C, ushort* __restrict__ C16,
    int M, int N, int K, int mode)
{
  __shared__ ushort As[128*32];
  __shared__ ushort Bs[128*32];
  int tid = threadIdx.x;
  int wid = tid >> 6, lane = tid & 63;
  int wr = wid >> 1, wc = wid & 1;
  int m0 = blockIdx.y*128, n0 = blockIdx.x*128;
  int lr = lane & 15, kq = lane >> 4;
  f32x4 acc[4][4] = {};
  for (int k0 = 0; k0 < K; k0 += 32) {
    #pragma unroll
    for (int it = 0; it < 2; it++) {
      int idx = tid + it*256;
      int row = idx >> 2, seg = idx & 3;
      uint4 va = *reinterpret_cast<const uint4*>(A + (long)(m0+row)*lda + k0 + seg*8);
      uint4 vb = *reinterpret_cast<const uint4*>(WT + (long)(n0+row)*K + k0 + seg*8);
      int off = (row*64 + seg*16) ^ ((row&7)<<4);
      *reinterpret_cast<uint4*>((char*)As + off) = va;
      *reinterpret_cast<uint4*>((char*)Bs + off) = vb;
    }
    __syncthreads();
    bf16x8 af[4], bg[4];
    #pragma unroll
    for (int i = 0; i < 4; i++) {
      int row = wr*64 + i*16 + lr;
      af[i] = *reinterpret_cast<const bf16x8*>((char*)As + ((row*64 + kq*16) ^ ((row&7)<<4)));
      int col = wc*64 + i*16 + lr;
      bg[i] = *reinterpret_cast<const bf16x8*>((char*)Bs + ((col*64 + kq*16) ^ ((col&7)<<4)));
    }
    #pragma unroll
    for (int i = 0; i < 4; i++)
      #pragma unroll
      for (int j = 0; j < 4; j++)
        acc[i][j] = __builtin_amdgcn_mfma_f32_16x16x32_bf16(af[i], bg[j], acc[i][j], 0, 0, 0);
    __syncthreads();
  }
  #pragma unroll
  for (int i = 0; i < 4; i++) {
    #pragma unroll
    for (int j = 0; j < 4; j++) {
      #pragma unroll
      for (int r = 0; r < 4; r++) {
        int m = m0 + wr*64 + i*16 + kq*4 + r;
        int n = n0 + wc*64 + j*16 + lr;
        float v = acc[i][j][r];
        long o = (long)m*N + n;
        if (mode == 0)      C[o] = v;
        else if (mode == 1) C[o] = sigmoidf_(v + bias[n]);
        else if (mode == 2) {
          v += bias[n];
          C[o] = fmaxf(v, 0.f) + log1pf(__expf(-fabsf(v)));
        }
        else if (mode == 3) C[o] = v + bias[n];
        else { C[o] = v; C16[o] = f2b(v); }
      }
    }
  }
}

// -------- causal dwconv(k=4) + silu; dual store f32 + bf16 --------
__global__ __launch_bounds__(256) void ssm_conv_k(
    const float* __restrict__ xz, const float* __restrict__ w,
    const float* __restrict__ bias, float* __restrict__ xs, ushort* __restrict__ xs16)
{
  long i = (long)blockIdx.x*256 + threadIdx.x;   // over NT*DI
  int d = (int)(i & (DI-1));
  long tok = i >> 10;
  int l = (int)(tok & (LL-1));
  const float* base = xz + (tok - l) * (2*DI) + d;
  float s = bias[d];
  #pragma unroll
  for (int k = 0; k < 4; k++) {
    int ll = l + k - 3;
    if (ll >= 0) s = fmaf(base[(long)ll*2*DI], w[d*4+k], s);
  }
  float r = siluf_(s);
  xs[i] = r;
  xs16[i] = f2b(r);
}

// -------- transpose delta (t-major) -> deltaT[d][t], dtuT = delta*u --------
__global__ __launch_bounds__(256) void trans_k(
    const float* __restrict__ dtraw, const float* __restrict__ xs,
    float* __restrict__ deltaT, float* __restrict__ dtuT)
{
  __shared__ float t1[32][33], t2[32][33];
  int d0 = blockIdx.x*32, t0 = blockIdx.y*32;
  int tx = threadIdx.x & 31, ty = threadIdx.x >> 5;  // 32 x 8
  #pragma unroll
  for (int i = 0; i < 4; i++) {
    long tok = t0 + ty + 8*i;
    float dv = dtraw[tok*DI + d0+tx];
    t1[ty+8*i][tx] = dv;
    t2[ty+8*i][tx] = dv * xs[tok*DI + d0+tx];
  }
  __syncthreads();
  #pragma unroll
  for (int i = 0; i < 4; i++) {
    int row = ty + 8*i;
    deltaT[(long)(d0+row)*NT + t0+tx] = t1[tx][row];
    dtuT  [(long)(d0+row)*NT + t0+tx] = t2[tx][row];
  }
}

// -------- selective scan: 1 wave = 2 channels, t in chunks of 32 --------
__global__ __launch_bounds__(64) void scan_k(
  const float* __restrict__ dtT, const float* __restrict__ dtuT,
  const float* __restrict__ dbl, const float* __restrict__ A_log,
  float* __restrict__ ygT)
{
  __shared__ float ys[2*32*36];
  int lane = threadIdx.x;        // 0..63
  int half = lane >> 5;
  int ln = lane & 31;            // n index; also t-slot index in reduce
  int ch = blockIdx.x*2 + half;  // 0..2047 = b*DI+d
  int b = ch >> 10, d = ch & (DI-1);
  float An = -__expf(A_log[d*DS + ln]);
  const float* dtp  = dtT  + (long)d*NT + (long)b*LL;
  const float* dtup = dtuT + (long)d*NT + (long)b*LL;
  const float* blp  = dbl + (long)b*LL*128 + DTR + ln;
  float* yp = ygT + (long)d*NT + (long)b*LL;
  float* lds = ys + half*(32*36);
  float h = 0.f;
  for (int c = 0; c < 64; c++) {
    int t0 = c*32;
    float dtv  = dtp[t0 + ln];
    float dtuv = dtup[t0 + ln];
    float Bv[32], Cv[32];
    #pragma unroll
    for (int tt = 0; tt < 32; tt++) {
      Bv[tt] = blp[(long)(t0+tt)*128];
      Cv[tt] = blp[(long)(t0+tt)*128 + DS];
    }
    float av[32], wv[32];
    #pragma unroll
    for (int tt = 0; tt < 32; tt++) {
      float dt_t  = __shfl(dtv,  tt, 32);
      float dtu_t = __shfl(dtuv, tt, 32);
      av[tt] = __expf(dt_t * An);
      wv[tt] = dtu_t * Bv[tt];
    }
    #pragma unroll
    for (int tt = 0; tt < 32; tt++) {
      h = fmaf(av[tt], h, wv[tt]);
      lds[tt*36 + ln] = h * Cv[tt];
    }
    __syncthreads();
    float y = 0.f;
    #pragma unroll
    for (int k = 0; k < 8; k++) {
      int kk = (k + (ln & 7)) & 7;
      const float4 v4 = *reinterpret_cast<const float4*>(&lds[ln*36 + kk*4]);
      y += v4.x + v4.y + v4.z + v4.w;
    }
    yp[t0 + ln] = y;
    __syncthreads();
  }
}

// -------- yg16[t][d] = bf16((ygT[d][t] + xs*D) * silu(z)) --------
__global__ __launch_bounds__(256) void mulz_k(
    const float* __restrict__ ygT, const float* __restrict__ xs,
    const float* __restrict__ xz, const float* __restrict__ Dp,
    ushort* __restrict__ yg16)
{
  __shared__ float tile[32][33];
  int d0 = blockIdx.x*32, t0 = blockIdx.y*32;
  int tx = threadIdx.x & 31, ty = threadIdx.x >> 5;  // 32 x 8
  #pragma unroll
  for (int k = 0; k < 4; k++)
    tile[ty+8*k][tx] = ygT[(long)(d0+ty+8*k)*NT + t0+tx];
  __syncthreads();
  #pragma unroll
  for (int k = 0; k < 4; k++) {
    long tok = t0+ty+8*k; int d = d0+tx;
    float u = xs[tok*DI + d];
    float z = xz[tok*2*DI + DI + d];
    yg16[tok*DI + d] = f2b((tile[tx][ty+8*k] + u*Dp[d]) * siluf_(z));
  }
}

// -------- combined = bf16(ssm*silu(ge) + xc*(1-gate)) --------
__global__ __launch_bounds__(256) void combine_k(
    const float* __restrict__ ssm, const float* __restrict__ gate,
    const float* __restrict__ xc, ushort* __restrict__ comb16)
{
  long i = (long)blockIdx.x*256 + threadIdx.x;  // over NT*DI
  int o = (int)(i & (DI-1));
  long tok = i >> 10;
  float gv = gate[tok*DM + (o>>1)];
  comb16[i] = f2b(ssm[i] * siluf_(gv) + xc[i] * (1.f - gv));
}

// -------- final LN over 512 of (pre + residual) --------
__global__ __launch_bounds__(256) void final_ln_k(
    const float* __restrict__ pre, const float* __restrict__ x,
    const float* __restrict__ g, const float* __restrict__ bt, float* __restrict__ out)
{
  int token = blockIdx.x;
  __shared__ float red[4];
  float v[2]; float sum = 0.f;
  #pragma unroll
  for (int i = 0; i < 2; i++) {
    int o = threadIdx.x + i*256;
    float t = pre[(long)token*DM+o] + x[(long)token*DM+o];
    v[i] = t; sum += t;
  }
  float mean = block_sum4(sum, red) * (1.f/DM);
  float vs = 0.f;
  #pragma unroll
  for (int i = 0; i < 2; i++) { float d = v[i]-mean; vs += d*d; }
  float var = block_sum4(vs, red) * (1.f/DM);
  float inv = rsqrtf(var + 1e-5f);
  #pragma unroll
  for (int i = 0; i < 2; i++) {
    int o = threadIdx.x + i*256;
    out[(long)token*DM + o] = (v[i]-mean)*inv*g[o] + bt[o];
  }
}

extern "C" void kernel_launch(void* const* d_in, const int* in_sizes, int n_in,
                              void* d_out, int out_size, void* d_ws, size_t ws_size,
                              hipStream_t stream)
{
  const float* x         = (const float*)d_in[0];
  const float* conv_w    = (const float*)d_in[1];
  const float* conv_b    = (const float*)d_in[2];
  const float* gate_w    = (const float*)d_in[3];
  const float* gate_b    = (const float*)d_in[4];
  const float* out_w     = (const float*)d_in[5];
  const float* out_b     = (const float*)d_in[6];
  const float* ln1_g     = (const float*)d_in[7];
  const float* ln1_b     = (const float*)d_in[8];
  const float* ln2_g     = (const float*)d_in[9];
  const float* ln2_b     = (const float*)d_in[10];
  const float* in_proj_w = (const float*)d_in[11];
  const float* ssm_conv_w= (const float*)d_in[12];
  const float* ssm_conv_b= (const float*)d_in[13];
  const float* x_proj_w  = (const float*)d_in[14];
  const float* dt_proj_w = (const float*)d_in[15];
  const float* dt_proj_b = (const float*)d_in[16];
  const float* A_log     = (const float*)d_in[17];
  const float* D_param   = (const float*)d_in[18];
  const float* out_proj_w= (const float*)d_in[19];

  float* ws    = (float*)d_ws;
  float* xz     = ws;                         // 8M f32
  float* xc     = xz    + (long)NT*2*DI;      // 4M
  float* gate   = xc    + (long)NT*DI;        // 2M
  float* xs     = gate  + (long)NT*DM;        // 4M
  float* dbl    = xs    + (long)NT*DI;        // 0.5M
  float* deltaT = dbl   + (long)NT*128;       // 4M
  float* dtuT   = deltaT+ (long)NT*DI;        // 4M
  float* ygT    = dtuT  + (long)NT*DI;        // 4M (dtraw first, then ygT)
  float* dtraw  = ygT;
  float* pre    = deltaT;  // reuse after scan
  float* ssm    = dtuT;    // reuse after scan

  ushort* b16   = (ushort*)(ygT + (long)NT*DI);
  ushort* x16   = b16;                        // 2M ushort
  ushort* dbl16 = b16;                        // reuse x16 region after gate gemm (0.5M)
  ushort* xc16  = b16   + (long)NT*DM;        // 4M ushort
  ushort* yg16  = xc16;                       // reuse after in_proj
  ushort* xs16  = xc16  + (long)NT*DI;        // 4M ushort
  ushort* comb16= xs16;                       // reuse after mulz
  ushort* wts   = xs16  + (long)NT*DI;
  ushort* gate_wT = wts;                          // 512*512
  ushort* in_wT   = gate_wT + (long)DM*DM;        // 2048*1024
  ushort* xp_wT   = in_wT   + (long)2*DI*DI;      // 128*1024
  ushort* dt_wT   = xp_wT   + (long)128*DI;       // 1024*64
  ushort* op_wT   = dt_wT   + (long)DI*DTR;       // 1024*1024
  ushort* ow_wT   = op_wT   + (long)DI*DI;        // 512*1024
  float* outp   = (float*)d_out;

  // converts
  convx_k<<<(NT*DM/4)/256, 256, 0, stream>>>(x, x16);
  wt_k<<<dim3(DM/32, DM/32),   256, 0, stream>>>(gate_w,     gate_wT, DM, DM);
  wt_k<<<dim3(2*DI/32, DI/32), 256, 0, stream>>>(in_proj_w,  in_wT,   DI, 2*DI);
  wt_k<<<dim3(128/32, DI/32),  256, 0, stream>>>(x_proj_w,   xp_wT,   DI, 128);
  wt_k<<<dim3(DI/32, DTR/32),  256, 0, stream>>>(dt_proj_w,  dt_wT,   DTR, DI);
  wt_k<<<dim3(DI/32, DI/32),   256, 0, stream>>>(out_proj_w, op_wT,   DI, DI);
  wt_k<<<dim3(DM/32, DI/32),   256, 0, stream>>>(out_w,      ow_wT,   DI, DM);

  conv_ln_k<<<NT, 256, 0, stream>>>(x, conv_w, conv_b, ln2_g, ln2_b, xc, xc16);
  bgemm_k<<<dim3(DM/128, NT/128), 256, 0, stream>>>(x16, DM, gate_wT, gate_b, gate, nullptr, NT, DM, DM, 1);
  bgemm_k<<<dim3(2*DI/128, NT/128), 256, 0, stream>>>(xc16, DI, in_wT, nullptr, xz, nullptr, NT, 2*DI, DI, 0);
  ssm_conv_k<<<(NT*DI)/256, 256, 0, stream>>>(xz, ssm_conv_w, ssm_conv_b, xs, xs16);
  bgemm_k<<<dim3(1, NT/128), 256, 0, stream>>>(xs16, DI, xp_wT, nullptr, dbl, dbl16, NT, 128, DI, 4);
  bgemm_k<<<dim3(DI/128, NT/128), 256, 0, stream>>>(dbl16, 128, dt_wT, dt_proj_b, dtraw, nullptr, NT, DI, DTR, 2);
  trans_k<<<dim3(DI/32, NT/32), 256, 0, stream>>>(dtraw, xs, deltaT, dtuT);
  scan_k<<<1024, 64, 0, stream>>>(deltaT, dtuT, dbl, A_log, ygT);
  mulz_k<<<dim3(DI/32, NT/32), 256, 0, stream>>>(ygT, xs, xz, D_param, yg16);
  bgemm_k<<<dim3(DI/128, NT/128), 256, 0, stream>>>(yg16, DI, op_wT, nullptr, ssm, nullptr, NT, DI, DI, 0);
  combine_k<<<(NT*DI)/256, 256, 0, stream>>>(ssm, gate, xc, comb16);
  bgemm_k<<<dim3(DM/128, NT/128), 256, 0, stream>>>(comb16, DI, ow_wT, out_b, pre, nullptr, NT, DM, DI, 3);
  final_ln_k<<<NT, 256, 0, stream>>>(pre, x, ln1_g, ln1_b, outp);
}

// Round 4
// 501.693 us; speedup vs baseline: 4.7854x; 1.0790x over previous
//
#include <hip/hip_runtime.h>
#include <cmath>

#define BB   2
#define LL   2048
#define DM   512
#define DI   1024
#define DS   32
#define DTR  64
#define NT   (BB*LL)   // 4096 tokens
#define NC   16        // chunks per sequence
#define CL   128       // chunk length (NC*CL == LL)

typedef short bf16x8 __attribute__((ext_vector_type(8)));
typedef float f32x4  __attribute__((ext_vector_type(4)));

__device__ __forceinline__ float sigmoidf_(float x){ return 1.f/(1.f+__expf(-x)); }
__device__ __forceinline__ float siluf_(float x){ return x*sigmoidf_(x); }
__device__ __forceinline__ ushort f2b(float f){
  union { float f; unsigned u; } x; x.f = f;
  unsigned r = (x.u + 0x7FFFu + ((x.u >> 16) & 1u)) >> 16;
  return (ushort)r;
}

// block-wide sum over 256 threads (4 waves)
__device__ __forceinline__ float block_sum4(float v, float* red) {
  #pragma unroll
  for (int off = 32; off >= 1; off >>= 1) v += __shfl_xor(v, off, 64);
  int w = threadIdx.x >> 6;
  __syncthreads();
  if ((threadIdx.x & 63) == 0) red[w] = v;
  __syncthreads();
  return red[0] + red[1] + red[2] + red[3];
}

// -------- f32 -> bf16 elementwise (x), 4 elems/thread --------
__global__ __launch_bounds__(256) void convx_k(
    const float* __restrict__ in, ushort* __restrict__ out)
{
  int i = blockIdx.x*256 + threadIdx.x;
  float4 v = reinterpret_cast<const float4*>(in)[i];
  ushort4 o; o.x=f2b(v.x); o.y=f2b(v.y); o.z=f2b(v.z); o.w=f2b(v.w);
  reinterpret_cast<ushort4*>(out)[i] = o;
}

// -------- weight transpose+convert: W[K][N] f32 -> WT[N][K] bf16 --------
__global__ __launch_bounds__(256) void wt_k(
    const float* __restrict__ W, ushort* __restrict__ WT, int K, int N)
{
  __shared__ float t[32][33];
  int n0 = blockIdx.x*32, k0 = blockIdx.y*32;
  int tx = threadIdx.x & 31, ty = threadIdx.x >> 5;  // 32 x 8
  #pragma unroll
  for (int i = 0; i < 4; i++)
    t[ty+8*i][tx] = W[(long)(k0+ty+8*i)*N + n0+tx];
  __syncthreads();
  #pragma unroll
  for (int i = 0; i < 4; i++)
    WT[(long)(n0+ty+8*i)*K + k0+tx] = f2b(t[tx][ty+8*i]);
}

// -------- fused dwconv(k=3, chan-mult 2) + silu + LN over 1024 --------
__global__ __launch_bounds__(256) void conv_ln_k(
    const float* __restrict__ x, const float* __restrict__ cw, const float* __restrict__ cb,
    const float* __restrict__ g, const float* __restrict__ bt,
    float* __restrict__ xc, ushort* __restrict__ xc16)
{
  int token = blockIdx.x;
  int l = token & (LL-1);
  __shared__ float red[4];
  float v[4]; float sum = 0.f;
  #pragma unroll
  for (int i = 0; i < 4; i++) {
    int o = threadIdx.x + i*256;
    int c = o >> 1;
    const float* xp = x + (long)token*DM + c;
    float s = cb[o];
    if (l >= 1)    s += xp[-DM] * cw[o*3+0];
                   s += xp[0]   * cw[o*3+1];
    if (l < LL-1)  s += xp[DM]  * cw[o*3+2];
    float t = siluf_(s);
    v[i] = t; sum += t;
  }
  float mean = block_sum4(sum, red) * (1.f/DI);
  float vs = 0.f;
  #pragma unroll
  for (int i = 0; i < 4; i++) { float d = v[i]-mean; vs += d*d; }
  float var = block_sum4(vs, red) * (1.f/DI);
  float inv = rsqrtf(var + 1e-5f);
  #pragma unroll
  for (int i = 0; i < 4; i++) {
    int o = threadIdx.x + i*256;
    float r = (v[i]-mean)*inv*g[o] + bt[o];
    xc[(long)token*DI + o] = r;
    xc16[(long)token*DI + o] = f2b(r);
  }
}

// -------- bf16 MFMA GEMM: 128x128 tile, BK=32, 4 waves --------
// mode: 0=plain, 1=sigmoid+bias, 2=softplus+bias, 3=bias, 4=dual f32+bf16
__global__ __launch_bounds__(256) void bgemm_k(
    const ushort* __restrict__ A, int lda,
    const ushort* __restrict__ WT,
    const float* __restrict__ bias,
    float* __restrict__ C, ushort* __restrict__ C16,
    int M, int N, int K, int mode)
{
  __shared__ ushort As[128*32];
  __shared__ ushort Bs[128*32];
  int tid = threadIdx.x;
  int wid = tid >> 6, lane = tid & 63;
  int wr = wid >> 1, wc = wid & 1;
  int m0 = blockIdx.y*128, n0 = blockIdx.x*128;
  int lr = lane & 15, kq = lane >> 4;
  f32x4 acc[4][4] = {};
  for (int k0 = 0; k0 < K; k0 += 32) {
    #pragma unroll
    for (int it = 0; it < 2; it++) {
      int idx = tid + it*256;
      int row = idx >> 2, seg = idx & 3;
      uint4 va = *reinterpret_cast<const uint4*>(A + (long)(m0+row)*lda + k0 + seg*8);
      uint4 vb = *reinterpret_cast<const uint4*>(WT + (long)(n0+row)*K + k0 + seg*8);
      int off = (row*64 + seg*16) ^ ((row&7)<<4);
      *reinterpret_cast<uint4*>((char*)As + off) = va;
      *reinterpret_cast<uint4*>((char*)Bs + off) = vb;
    }
    __syncthreads();
    bf16x8 af[4], bg[4];
    #pragma unroll
    for (int i = 0; i < 4; i++) {
      int row = wr*64 + i*16 + lr;
      af[i] = *reinterpret_cast<const bf16x8*>((char*)As + ((row*64 + kq*16) ^ ((row&7)<<4)));
      int col = wc*64 + i*16 + lr;
      bg[i] = *reinterpret_cast<const bf16x8*>((char*)Bs + ((col*64 + kq*16) ^ ((col&7)<<4)));
    }
    #pragma unroll
    for (int i = 0; i < 4; i++)
      #pragma unroll
      for (int j = 0; j < 4; j++)
        acc[i][j] = __builtin_amdgcn_mfma_f32_16x16x32_bf16(af[i], bg[j], acc[i][j], 0, 0, 0);
    __syncthreads();
  }
  #pragma unroll
  for (int i = 0; i < 4; i++) {
    #pragma unroll
    for (int j = 0; j < 4; j++) {
      #pragma unroll
      for (int r = 0; r < 4; r++) {
        int m = m0 + wr*64 + i*16 + kq*4 + r;
        int n = n0 + wc*64 + j*16 + lr;
        float v = acc[i][j][r];
        long o = (long)m*N + n;
        if (mode == 0)      C[o] = v;
        else if (mode == 1) C[o] = sigmoidf_(v + bias[n]);
        else if (mode == 2) {
          v += bias[n];
          C[o] = fmaxf(v, 0.f) + log1pf(__expf(-fabsf(v)));
        }
        else if (mode == 3) C[o] = v + bias[n];
        else { C[o] = v; C16[o] = f2b(v); }
      }
    }
  }
}

// -------- causal dwconv(k=4) + silu; dual store f32 + bf16 --------
__global__ __launch_bounds__(256) void ssm_conv_k(
    const float* __restrict__ xz, const float* __restrict__ w,
    const float* __restrict__ bias, float* __restrict__ xs, ushort* __restrict__ xs16)
{
  long i = (long)blockIdx.x*256 + threadIdx.x;   // over NT*DI
  int d = (int)(i & (DI-1));
  long tok = i >> 10;
  int l = (int)(tok & (LL-1));
  const float* base = xz + (tok - l) * (2*DI) + d;
  float s = bias[d];
  #pragma unroll
  for (int k = 0; k < 4; k++) {
    int ll = l + k - 3;
    if (ll >= 0) s = fmaf(base[(long)ll*2*DI], w[d*4+k], s);
  }
  float r = siluf_(s);
  xs[i] = r;
  xs16[i] = f2b(r);
}

// -------- transpose delta (t-major) -> deltaT[d][t], dtuT = delta*u --------
__global__ __launch_bounds__(256) void trans_k(
    const float* __restrict__ dtraw, const float* __restrict__ xs,
    float* __restrict__ deltaT, float* __restrict__ dtuT)
{
  __shared__ float t1[32][33], t2[32][33];
  int d0 = blockIdx.x*32, t0 = blockIdx.y*32;
  int tx = threadIdx.x & 31, ty = threadIdx.x >> 5;  // 32 x 8
  #pragma unroll
  for (int i = 0; i < 4; i++) {
    long tok = t0 + ty + 8*i;
    float dv = dtraw[tok*DI + d0+tx];
    t1[ty+8*i][tx] = dv;
    t2[ty+8*i][tx] = dv * xs[tok*DI + d0+tx];
  }
  __syncthreads();
  #pragma unroll
  for (int i = 0; i < 4; i++) {
    int row = ty + 8*i;
    deltaT[(long)(d0+row)*NT + t0+tx] = t1[tx][row];
    dtuT  [(long)(d0+row)*NT + t0+tx] = t2[tx][row];
  }
}

// ======== chunked selective scan ========
// phase 1: per (channel-pair, chunk): local scan from h=0 -> hend, sumdt
__global__ __launch_bounds__(64) void scan1_k(
  const float* __restrict__ dtT, const float* __restrict__ dtuT,
  const float* __restrict__ dbl, const float* __restrict__ A_log,
  float* __restrict__ hend, float* __restrict__ sumdt)
{
  int lane = threadIdx.x, half = lane >> 5, ln = lane & 31;
  int bi = blockIdx.x;
  int pair = bi >> 4, c = bi & (NC-1);
  int ch = pair*2 + half;
  int b = ch >> 10, d = ch & (DI-1);
  float An = -__expf(A_log[d*DS + ln]);
  const float* dtp  = dtT  + (long)d*NT + b*LL + c*CL;
  const float* dtup = dtuT + (long)d*NT + b*LL + c*CL;
  const float* blp  = dbl + ((long)b*LL + c*CL)*128 + DTR + ln;
  float h = 0.f, sdt = 0.f;
  for (int g = 0; g < CL/32; g++) {
    float dtv  = dtp[g*32 + ln];
    float dtuv = dtup[g*32 + ln];
    float Bv[32];
    #pragma unroll
    for (int tt = 0; tt < 32; tt++) Bv[tt] = blp[(long)(g*32+tt)*128];
    float s = dtv;
    #pragma unroll
    for (int off = 16; off >= 1; off >>= 1) s += __shfl_xor(s, off, 32);
    sdt += s;
    float av[32], wv[32];
    #pragma unroll
    for (int tt = 0; tt < 32; tt++) {
      av[tt] = __expf(__shfl(dtv, tt, 32) * An);
      wv[tt] = __shfl(dtuv, tt, 32) * Bv[tt];
    }
    #pragma unroll
    for (int tt = 0; tt < 32; tt++) h = fmaf(av[tt], h, wv[tt]);
  }
  hend[((long)c*2048 + ch)*32 + ln] = h;
  if (ln == 0) sumdt[c*2048 + ch] = sdt;
}

// phase 2: sequential chunk combine; hend[c] overwritten with initial state S_c
__global__ __launch_bounds__(256) void scan2_k(
  float* __restrict__ hend, const float* __restrict__ sumdt,
  const float* __restrict__ A_log)
{
  int idx = blockIdx.x*256 + threadIdx.x;   // 0..65535
  int ch = idx >> 5, n = idx & 31;
  int d = ch & (DI-1);
  float An = -__expf(A_log[d*DS + n]);
  float H = 0.f;
  for (int c = 0; c < NC; c++) {
    long o = ((long)c*2048 + ch)*32 + n;
    float he = hend[o];
    float P = __expf(An * sumdt[c*2048 + ch]);
    hend[o] = H;
    H = P*H + he;
  }
}

// phase 3: local scan with true initial state; writes ygT
__global__ __launch_bounds__(64) void scan3_k(
  const float* __restrict__ dtT, const float* __restrict__ dtuT,
  const float* __restrict__ dbl, const float* __restrict__ A_log,
  const float* __restrict__ hini, float* __restrict__ ygT)
{
  __shared__ float ys[2*32*33];
  int lane = threadIdx.x, half = lane >> 5, ln = lane & 31;
  int bi = blockIdx.x;
  int pair = bi >> 4, c = bi & (NC-1);
  int ch = pair*2 + half;
  int b = ch >> 10, d = ch & (DI-1);
  float An = -__expf(A_log[d*DS + ln]);
  const float* dtp  = dtT  + (long)d*NT + b*LL + c*CL;
  const float* dtup = dtuT + (long)d*NT + b*LL + c*CL;
  const float* blp  = dbl + ((long)b*LL + c*CL)*128 + DTR + ln;
  float* yp = ygT + (long)d*NT + b*LL + c*CL;
  float* lds = ys + half*(32*33);
  float h = hini[((long)c*2048 + ch)*32 + ln];
  for (int g = 0; g < CL/32; g++) {
    float dtv  = dtp[g*32 + ln];
    float dtuv = dtup[g*32 + ln];
    float Bv[32], Cv[32];
    #pragma unroll
    for (int tt = 0; tt < 32; tt++) {
      Bv[tt] = blp[(long)(g*32+tt)*128];
      Cv[tt] = blp[(long)(g*32+tt)*128 + DS];
    }
    float av[32], wv[32];
    #pragma unroll
    for (int tt = 0; tt < 32; tt++) {
      av[tt] = __expf(__shfl(dtv, tt, 32) * An);
      wv[tt] = __shfl(dtuv, tt, 32) * Bv[tt];
    }
    #pragma unroll
    for (int tt = 0; tt < 32; tt++) {
      h = fmaf(av[tt], h, wv[tt]);
      lds[tt*33 + ln] = h * Cv[tt];
    }
    __syncthreads();
    float y = 0.f;
    #pragma unroll
    for (int k = 0; k < 32; k++) y += lds[ln*33 + k];
    yp[g*32 + ln] = y;
    __syncthreads();
  }
}

// -------- yg16[t][d] = bf16((ygT[d][t] + xs*D) * silu(z)) --------
__global__ __launch_bounds__(256) void mulz_k(
    const float* __restrict__ ygT, const float* __restrict__ xs,
    const float* __restrict__ xz, const float* __restrict__ Dp,
    ushort* __restrict__ yg16)
{
  __shared__ float tile[32][33];
  int d0 = blockIdx.x*32, t0 = blockIdx.y*32;
  int tx = threadIdx.x & 31, ty = threadIdx.x >> 5;  // 32 x 8
  #pragma unroll
  for (int k = 0; k < 4; k++)
    tile[ty+8*k][tx] = ygT[(long)(d0+ty+8*k)*NT + t0+tx];
  __syncthreads();
  #pragma unroll
  for (int k = 0; k < 4; k++) {
    long tok = t0+ty+8*k; int d = d0+tx;
    float u = xs[tok*DI + d];
    float z = xz[tok*2*DI + DI + d];
    yg16[tok*DI + d] = f2b((tile[tx][ty+8*k] + u*Dp[d]) * siluf_(z));
  }
}

// -------- combined = bf16(ssm*silu(ge) + xc*(1-gate)) --------
__global__ __launch_bounds__(256) void combine_k(
    const float* __restrict__ ssm, const float* __restrict__ gate,
    const float* __restrict__ xc, ushort* __restrict__ comb16)
{
  long i = (long)blockIdx.x*256 + threadIdx.x;  // over NT*DI
  int o = (int)(i & (DI-1));
  long tok = i >> 10;
  float gv = gate[tok*DM + (o>>1)];
  comb16[i] = f2b(ssm[i] * siluf_(gv) + xc[i] * (1.f - gv));
}

// -------- final LN over 512 of (pre + residual) --------
__global__ __launch_bounds__(256) void final_ln_k(
    const float* __restrict__ pre, const float* __restrict__ x,
    const float* __restrict__ g, const float* __restrict__ bt, float* __restrict__ out)
{
  int token = blockIdx.x;
  __shared__ float red[4];
  float v[2]; float sum = 0.f;
  #pragma unroll
  for (int i = 0; i < 2; i++) {
    int o = threadIdx.x + i*256;
    float t = pre[(long)token*DM+o] + x[(long)token*DM+o];
    v[i] = t; sum += t;
  }
  float mean = block_sum4(sum, red) * (1.f/DM);
  float vs = 0.f;
  #pragma unroll
  for (int i = 0; i < 2; i++) { float d = v[i]-mean; vs += d*d; }
  float var = block_sum4(vs, red) * (1.f/DM);
  float inv = rsqrtf(var + 1e-5f);
  #pragma unroll
  for (int i = 0; i < 2; i++) {
    int o = threadIdx.x + i*256;
    out[(long)token*DM + o] = (v[i]-mean)*inv*g[o] + bt[o];
  }
}

extern "C" void kernel_launch(void* const* d_in, const int* in_sizes, int n_in,
                              void* d_out, int out_size, void* d_ws, size_t ws_size,
                              hipStream_t stream)
{
  const float* x         = (const float*)d_in[0];
  const float* conv_w    = (const float*)d_in[1];
  const float* conv_b    = (const float*)d_in[2];
  const float* gate_w    = (const float*)d_in[3];
  const float* gate_b    = (const float*)d_in[4];
  const float* out_w     = (const float*)d_in[5];
  const float* out_b     = (const float*)d_in[6];
  const float* ln1_g     = (const float*)d_in[7];
  const float* ln1_b     = (const float*)d_in[8];
  const float* ln2_g     = (const float*)d_in[9];
  const float* ln2_b     = (const float*)d_in[10];
  const float* in_proj_w = (const float*)d_in[11];
  const float* ssm_conv_w= (const float*)d_in[12];
  const float* ssm_conv_b= (const float*)d_in[13];
  const float* x_proj_w  = (const float*)d_in[14];
  const float* dt_proj_w = (const float*)d_in[15];
  const float* dt_proj_b = (const float*)d_in[16];
  const float* A_log     = (const float*)d_in[17];
  const float* D_param   = (const float*)d_in[18];
  const float* out_proj_w= (const float*)d_in[19];

  float* ws    = (float*)d_ws;
  float* xz     = ws;                         // 8M f32
  float* xc     = xz    + (long)NT*2*DI;      // 4M
  float* gate   = xc    + (long)NT*DI;        // 2M
  float* xs     = gate  + (long)NT*DM;        // 4M
  float* dbl    = xs    + (long)NT*DI;        // 0.5M
  float* deltaT = dbl   + (long)NT*128;       // 4M
  float* dtuT   = deltaT+ (long)NT*DI;        // 4M
  float* ygT    = dtuT  + (long)NT*DI;        // 4M (dtraw first, then ygT)
  float* dtraw  = ygT;
  float* pre    = deltaT;  // reuse after scan
  float* ssm    = dtuT;    // reuse after scan

  ushort* b16   = (ushort*)(ygT + (long)NT*DI);
  ushort* x16   = b16;                        // 2M ushort
  ushort* dbl16 = b16;                        // reuse after gate gemm (0.5M ush)
  float*  hend  = (float*)b16;                // 1M f32 (=4MB) reuse after dt_proj gemm
  ushort* xc16  = b16   + (long)NT*DM;        // 4M ushort
  ushort* yg16  = xc16;                       // reuse after in_proj
  ushort* xs16  = xc16  + (long)NT*DI;        // 4M ushort
  ushort* comb16= xs16;                       // reuse after mulz
  ushort* wts   = xs16  + (long)NT*DI;
  ushort* gate_wT = wts;                          // 512*512
  ushort* in_wT   = gate_wT + (long)DM*DM;        // 2048*1024
  ushort* xp_wT   = in_wT   + (long)2*DI*DI;      // 128*1024
  ushort* dt_wT   = xp_wT   + (long)128*DI;       // 1024*64
  ushort* op_wT   = dt_wT   + (long)DI*DTR;       // 1024*1024
  ushort* ow_wT   = op_wT   + (long)DI*DI;        // 512*1024
  float*  sumdt   = (float*)(ow_wT + (long)DM*DI);// NC*2048 f32 (128KB)
  float* outp   = (float*)d_out;

  // converts
  convx_k<<<(NT*DM/4)/256, 256, 0, stream>>>(x, x16);
  wt_k<<<dim3(DM/32, DM/32),   256, 0, stream>>>(gate_w,     gate_wT, DM, DM);
  wt_k<<<dim3(2*DI/32, DI/32), 256, 0, stream>>>(in_proj_w,  in_wT,   DI, 2*DI);
  wt_k<<<dim3(128/32, DI/32),  256, 0, stream>>>(x_proj_w,   xp_wT,   DI, 128);
  wt_k<<<dim3(DI/32, DTR/32),  256, 0, stream>>>(dt_proj_w,  dt_wT,   DTR, DI);
  wt_k<<<dim3(DI/32, DI/32),   256, 0, stream>>>(out_proj_w, op_wT,   DI, DI);
  wt_k<<<dim3(DM/32, DI/32),   256, 0, stream>>>(out_w,      ow_wT,   DI, DM);

  conv_ln_k<<<NT, 256, 0, stream>>>(x, conv_w, conv_b, ln2_g, ln2_b, xc, xc16);
  bgemm_k<<<dim3(DM/128, NT/128), 256, 0, stream>>>(x16, DM, gate_wT, gate_b, gate, nullptr, NT, DM, DM, 1);
  bgemm_k<<<dim3(2*DI/128, NT/128), 256, 0, stream>>>(xc16, DI, in_wT, nullptr, xz, nullptr, NT, 2*DI, DI, 0);
  ssm_conv_k<<<(NT*DI)/256, 256, 0, stream>>>(xz, ssm_conv_w, ssm_conv_b, xs, xs16);
  bgemm_k<<<dim3(1, NT/128), 256, 0, stream>>>(xs16, DI, xp_wT, nullptr, dbl, dbl16, NT, 128, DI, 4);
  bgemm_k<<<dim3(DI/128, NT/128), 256, 0, stream>>>(dbl16, 128, dt_wT, dt_proj_b, dtraw, nullptr, NT, DI, DTR, 2);
  trans_k<<<dim3(DI/32, NT/32), 256, 0, stream>>>(dtraw, xs, deltaT, dtuT);
  scan1_k<<<1024*NC, 64, 0, stream>>>(deltaT, dtuT, dbl, A_log, hend, sumdt);
  scan2_k<<<(2048*32)/256, 256, 0, stream>>>(hend, sumdt, A_log);
  scan3_k<<<1024*NC, 64, 0, stream>>>(deltaT, dtuT, dbl, A_log, hend, ygT);
  mulz_k<<<dim3(DI/32, NT/32), 256, 0, stream>>>(ygT, xs, xz, D_param, yg16);
  bgemm_k<<<dim3(DI/128, NT/128), 256, 0, stream>>>(yg16, DI, op_wT, nullptr, ssm, nullptr, NT, DI, DI, 0);
  combine_k<<<(NT*DI)/256, 256, 0, stream>>>(ssm, gate, xc, comb16);
  bgemm_k<<<dim3(DM/128, NT/128), 256, 0, stream>>>(comb16, DI, ow_wT, out_b, pre, nullptr, NT, DM, DI, 3);
  final_ln_k<<<NT, 256, 0, stream>>>(pre, x, ln1_g, ln1_b, outp);
}

// Round 5
// 404.762 us; speedup vs baseline: 5.9314x; 1.2395x over previous
//
#include <hip/hip_runtime.h>
#include <cmath>

#define BB   2
#define LL   2048
#define DM   512
#define DI   1024
#define DS   32
#define DTR  64
#define NT   (BB*LL)   // 4096 tokens
#define NC   16        // chunks per sequence
#define CL   128       // chunk length (NC*CL == LL)
#define KS   8         // x_proj K-slices

typedef short bf16x8 __attribute__((ext_vector_type(8)));
typedef float f32x4  __attribute__((ext_vector_type(4)));

__device__ __forceinline__ float sigmoidf_(float x){ return 1.f/(1.f+__expf(-x)); }
__device__ __forceinline__ float siluf_(float x){ return x*sigmoidf_(x); }
__device__ __forceinline__ ushort f2b(float f){
  union { float f; unsigned u; } x; x.f = f;
  unsigned r = (x.u + 0x7FFFu + ((x.u >> 16) & 1u)) >> 16;
  return (ushort)r;
}
__device__ __forceinline__ float b2f(ushort v){
  union { unsigned u; float f; } x; x.u = ((unsigned)v) << 16; return x.f;
}

// block-wide sum over 256 threads (4 waves)
__device__ __forceinline__ float block_sum4(float v, float* red) {
  #pragma unroll
  for (int off = 32; off >= 1; off >>= 1) v += __shfl_xor(v, off, 64);
  int w = threadIdx.x >> 6;
  __syncthreads();
  if ((threadIdx.x & 63) == 0) red[w] = v;
  __syncthreads();
  return red[0] + red[1] + red[2] + red[3];
}

// -------- f32 -> bf16 elementwise (x), 4 elems/thread --------
__global__ __launch_bounds__(256) void convx_k(
    const float* __restrict__ in, ushort* __restrict__ out)
{
  int i = blockIdx.x*256 + threadIdx.x;
  float4 v = reinterpret_cast<const float4*>(in)[i];
  ushort4 o; o.x=f2b(v.x); o.y=f2b(v.y); o.z=f2b(v.z); o.w=f2b(v.w);
  reinterpret_cast<ushort4*>(out)[i] = o;
}

// -------- all weight transposes in ONE launch: W[K][N] f32 -> WT[N][K] bf16 --------
__global__ __launch_bounds__(256) void wtall_k(
  const float* __restrict__ s0, const float* __restrict__ s1, const float* __restrict__ s2,
  const float* __restrict__ s3, const float* __restrict__ s4, const float* __restrict__ s5,
  ushort* __restrict__ d0, ushort* __restrict__ d1, ushort* __restrict__ d2,
  ushort* __restrict__ d3, ushort* __restrict__ d4, ushort* __restrict__ d5)
{
  // jobs: gate(512,512) in(1024,2048) xp(1024,128) dt(64,1024) op(1024,1024) ow(1024,512)
  const int pre[7] = {0,256,2304,2432,2496,3520,4032};
  const int Ks[6] = {512,1024,1024,64,1024,1024};
  const int Ns[6] = {512,2048,128,1024,1024,512};
  int bid = blockIdx.x;
  int j = 0;
  while (bid >= pre[j+1]) j++;
  int rem = bid - pre[j];
  int gx = Ns[j] >> 5;
  int n0 = (rem % gx)*32, k0 = (rem / gx)*32;
  const float* W = j==0?s0: j==1?s1: j==2?s2: j==3?s3: j==4?s4: s5;
  ushort* WT     = j==0?d0: j==1?d1: j==2?d2: j==3?d3: j==4?d4: d5;
  int K = Ks[j], N = Ns[j];
  __shared__ float t[32][33];
  int tx = threadIdx.x & 31, ty = threadIdx.x >> 5;
  #pragma unroll
  for (int i = 0; i < 4; i++)
    t[ty+8*i][tx] = W[(long)(k0+ty+8*i)*N + n0+tx];
  __syncthreads();
  #pragma unroll
  for (int i = 0; i < 4; i++)
    WT[(long)(n0+ty+8*i)*K + k0+tx] = f2b(t[tx][ty+8*i]);
}

// -------- fused dwconv(k=3, chan-mult 2) + silu + LN over 1024 --------
__global__ __launch_bounds__(256) void conv_ln_k(
    const float* __restrict__ x, const float* __restrict__ cw, const float* __restrict__ cb,
    const float* __restrict__ g, const float* __restrict__ bt,
    float* __restrict__ xc, ushort* __restrict__ xc16)
{
  int token = blockIdx.x;
  int l = token & (LL-1);
  __shared__ float red[4];
  float v[4]; float sum = 0.f;
  #pragma unroll
  for (int i = 0; i < 4; i++) {
    int o = threadIdx.x + i*256;
    int c = o >> 1;
    const float* xp = x + (long)token*DM + c;
    float s = cb[o];
    if (l >= 1)    s += xp[-DM] * cw[o*3+0];
                   s += xp[0]   * cw[o*3+1];
    if (l < LL-1)  s += xp[DM]  * cw[o*3+2];
    float t = siluf_(s);
    v[i] = t; sum += t;
  }
  float mean = block_sum4(sum, red) * (1.f/DI);
  float vs = 0.f;
  #pragma unroll
  for (int i = 0; i < 4; i++) { float d = v[i]-mean; vs += d*d; }
  float var = block_sum4(vs, red) * (1.f/DI);
  float inv = rsqrtf(var + 1e-5f);
  #pragma unroll
  for (int i = 0; i < 4; i++) {
    int o = threadIdx.x + i*256;
    float r = (v[i]-mean)*inv*g[o] + bt[o];
    xc[(long)token*DI + o] = r;
    xc16[(long)token*DI + o] = f2b(r);
  }
}

// -------- bf16 MFMA GEMM: 128x128 tile, BK=32, 4 waves --------
// mode: 0=plain, 1=sigmoid+bias, 3=bias
__global__ __launch_bounds__(256) void bgemm_k(
    const ushort* __restrict__ A, int lda,
    const ushort* __restrict__ WT,
    const float* __restrict__ bias,
    float* __restrict__ C,
    int M, int N, int K, int mode)
{
  __shared__ ushort As[128*32];
  __shared__ ushort Bs[128*32];
  int tid = threadIdx.x;
  int wid = tid >> 6, lane = tid & 63;
  int wr = wid >> 1, wc = wid & 1;
  int m0 = blockIdx.y*128, n0 = blockIdx.x*128;
  int lr = lane & 15, kq = lane >> 4;
  f32x4 acc[4][4] = {};
  for (int k0 = 0; k0 < K; k0 += 32) {
    #pragma unroll
    for (int it = 0; it < 2; it++) {
      int idx = tid + it*256;
      int row = idx >> 2, seg = idx & 3;
      uint4 va = *reinterpret_cast<const uint4*>(A + (long)(m0+row)*lda + k0 + seg*8);
      uint4 vb = *reinterpret_cast<const uint4*>(WT + (long)(n0+row)*K + k0 + seg*8);
      int off = (row*64 + seg*16) ^ ((row&7)<<4);
      *reinterpret_cast<uint4*>((char*)As + off) = va;
      *reinterpret_cast<uint4*>((char*)Bs + off) = vb;
    }
    __syncthreads();
    bf16x8 af[4], bg[4];
    #pragma unroll
    for (int i = 0; i < 4; i++) {
      int row = wr*64 + i*16 + lr;
      af[i] = *reinterpret_cast<const bf16x8*>((char*)As + ((row*64 + kq*16) ^ ((row&7)<<4)));
      int col = wc*64 + i*16 + lr;
      bg[i] = *reinterpret_cast<const bf16x8*>((char*)Bs + ((col*64 + kq*16) ^ ((col&7)<<4)));
    }
    #pragma unroll
    for (int i = 0; i < 4; i++)
      #pragma unroll
      for (int j = 0; j < 4; j++)
        acc[i][j] = __builtin_amdgcn_mfma_f32_16x16x32_bf16(af[i], bg[j], acc[i][j], 0, 0, 0);
    __syncthreads();
  }
  #pragma unroll
  for (int i = 0; i < 4; i++) {
    #pragma unroll
    for (int j = 0; j < 4; j++) {
      #pragma unroll
      for (int r = 0; r < 4; r++) {
        int m = m0 + wr*64 + i*16 + kq*4 + r;
        int n = n0 + wc*64 + j*16 + lr;
        float v = acc[i][j][r];
        long o = (long)m*N + n;
        if (mode == 0)      C[o] = v;
        else if (mode == 1) C[o] = sigmoidf_(v + bias[n]);
        else                C[o] = v + bias[n];
      }
    }
  }
}

// -------- x_proj split-K: partial[ks][t][n] over K-slice of 128 --------
__global__ __launch_bounds__(256) void xproj_k(
    const ushort* __restrict__ A,      // xs16 [NT][DI]
    const ushort* __restrict__ WT,     // xp_wT [128][DI]
    float* __restrict__ P)             // dblP [KS][NT][128]
{
  __shared__ ushort As[128*32];
  __shared__ ushort Bs[128*32];
  int tid = threadIdx.x;
  int wid = tid >> 6, lane = tid & 63;
  int wr = wid >> 1, wc = wid & 1;
  int m0 = blockIdx.y*128;
  int ks = blockIdx.x;
  int lr = lane & 15, kq = lane >> 4;
  f32x4 acc[4][4] = {};
  for (int k0 = ks*128; k0 < ks*128 + 128; k0 += 32) {
    #pragma unroll
    for (int it = 0; it < 2; it++) {
      int idx = tid + it*256;
      int row = idx >> 2, seg = idx & 3;
      uint4 va = *reinterpret_cast<const uint4*>(A + (long)(m0+row)*DI + k0 + seg*8);
      uint4 vb = *reinterpret_cast<const uint4*>(WT + (long)row*DI + k0 + seg*8);
      int off = (row*64 + seg*16) ^ ((row&7)<<4);
      *reinterpret_cast<uint4*>((char*)As + off) = va;
      *reinterpret_cast<uint4*>((char*)Bs + off) = vb;
    }
    __syncthreads();
    bf16x8 af[4], bg[4];
    #pragma unroll
    for (int i = 0; i < 4; i++) {
      int row = wr*64 + i*16 + lr;
      af[i] = *reinterpret_cast<const bf16x8*>((char*)As + ((row*64 + kq*16) ^ ((row&7)<<4)));
      int col = wc*64 + i*16 + lr;
      bg[i] = *reinterpret_cast<const bf16x8*>((char*)Bs + ((col*64 + kq*16) ^ ((col&7)<<4)));
    }
    #pragma unroll
    for (int i = 0; i < 4; i++)
      #pragma unroll
      for (int j = 0; j < 4; j++)
        acc[i][j] = __builtin_amdgcn_mfma_f32_16x16x32_bf16(af[i], bg[j], acc[i][j], 0, 0, 0);
    __syncthreads();
  }
  float* C = P + (long)ks*NT*128;
  #pragma unroll
  for (int i = 0; i < 4; i++)
    #pragma unroll
    for (int j = 0; j < 4; j++)
      #pragma unroll
      for (int r = 0; r < 4; r++) {
        int m = m0 + wr*64 + i*16 + kq*4 + r;
        int n = wc*64 + j*16 + lr;
        C[(long)m*128 + n] = acc[i][j][r];
      }
}

// -------- reduce KS partials + transpose -> dblT[128][NT] --------
__global__ __launch_bounds__(256) void dblred_k(
    const float* __restrict__ P, float* __restrict__ dblT)
{
  __shared__ float t[32][33];
  int t0 = blockIdx.x*32, n0 = blockIdx.y*32;
  int tx = threadIdx.x & 31, ty = threadIdx.x >> 5;
  #pragma unroll
  for (int i = 0; i < 4; i++) {
    float s = 0.f;
    long o = (long)(t0+ty+8*i)*128 + n0+tx;
    #pragma unroll
    for (int sl = 0; sl < KS; sl++) s += P[(long)sl*NT*128 + o];
    t[ty+8*i][tx] = s;
  }
  __syncthreads();
  #pragma unroll
  for (int i = 0; i < 4; i++)
    dblT[(long)(n0+ty+8*i)*NT + t0+tx] = t[tx][ty+8*i];
}

// -------- dt_proj fused: deltaT[d][t] = softplus(dt_wT[d][:] @ dblT[:64][t] + b[d]) --------
__global__ __launch_bounds__(256) void dtg_k(
    const float* __restrict__ dblT, const ushort* __restrict__ dtw,
    const float* __restrict__ bias, float* __restrict__ deltaT)
{
  __shared__ ushort Asub[64*72];   // [d][k] padded
  __shared__ float Bsub[64*65];    // [k][t] padded
  int tid = threadIdx.x;
  int d0 = blockIdx.y*64, t0 = blockIdx.x*64;
  {
    int row = tid >> 2, seg = tid & 3;
    const uint4* src = reinterpret_cast<const uint4*>(dtw + (long)(d0+row)*64 + seg*16);
    uint4* dst = reinterpret_cast<uint4*>(Asub + row*72 + seg*16);
    dst[0] = src[0]; dst[1] = src[1];
  }
  {
    int row = tid >> 2, seg = tid & 3;
    const float4* src = reinterpret_cast<const float4*>(dblT + (long)row*NT + t0 + seg*16);
    float* dst = Bsub + row*65 + seg*16;
    #pragma unroll
    for (int q = 0; q < 4; q++) {
      float4 v = src[q];
      dst[q*4+0]=v.x; dst[q*4+1]=v.y; dst[q*4+2]=v.z; dst[q*4+3]=v.w;
    }
  }
  __syncthreads();
  int wid = tid >> 6, lane = tid & 63, lr = lane & 15, kq = lane >> 4;
  f32x4 acc[4] = {};
  #pragma unroll
  for (int kstep = 0; kstep < 2; kstep++) {
    bf16x8 af = *reinterpret_cast<const bf16x8*>(Asub + (wid*16+lr)*72 + kstep*32 + kq*8);
    #pragma unroll
    for (int j = 0; j < 4; j++) {
      bf16x8 bg;
      #pragma unroll
      for (int e = 0; e < 8; e++)
        bg[e] = (short)f2b(Bsub[(kstep*32 + kq*8 + e)*65 + j*16 + lr]);
      acc[j] = __builtin_amdgcn_mfma_f32_16x16x32_bf16(af, bg, acc[j], 0, 0, 0);
    }
  }
  #pragma unroll
  for (int j = 0; j < 4; j++)
    #pragma unroll
    for (int r = 0; r < 4; r++) {
      int d = d0 + wid*16 + kq*4 + r;
      float v = acc[j][r] + bias[d];
      v = fmaxf(v, 0.f) + log1pf(__expf(-fabsf(v)));
      deltaT[(long)d*NT + t0 + j*16 + lr] = v;
    }
}

// -------- tiled causal dwconv(k=4) + silu: writes xs16 (t-major) + xsT (d-major) --------
__global__ __launch_bounds__(256) void ssm_conv2_k(
    const float* __restrict__ xz, const float* __restrict__ w4,
    const float* __restrict__ bias, ushort* __restrict__ xs16,
    float* __restrict__ xsT)
{
  __shared__ float tile[64][65];
  int d0 = blockIdx.x*64, t0 = blockIdx.y*64;
  int wv = threadIdx.x >> 6, lane = threadIdx.x & 63;
  int d = d0 + lane;
  float w0 = w4[d*4+0], w1 = w4[d*4+1], w2 = w4[d*4+2], w3 = w4[d*4+3];
  float bs = bias[d];
  int tstart = t0 + wv*16;
  int lstart = tstart & (LL-1);
  const float* xp = xz + (long)tstart*2*DI + d;
  float x0 = (lstart >= 3) ? xp[-3*2*DI] : 0.f;
  float x1 = (lstart >= 2) ? xp[-2*2*DI] : 0.f;
  float x2 = (lstart >= 1) ? xp[-1*2*DI] : 0.f;
  #pragma unroll
  for (int i = 0; i < 16; i++) {
    float x3 = xp[(long)i*2*DI];
    float s = bs + w0*x0 + w1*x1 + w2*x2 + w3*x3;
    tile[wv*16+i][lane] = siluf_(s);
    x0 = x1; x1 = x2; x2 = x3;
  }
  __syncthreads();
  #pragma unroll
  for (int i = 0; i < 16; i++) {
    int tt = wv + i*4;
    xs16[(long)(t0+tt)*DI + d0 + lane] = f2b(tile[tt][lane]);
  }
  #pragma unroll
  for (int i = 0; i < 16; i++) {
    int dd = wv + i*4;
    xsT[(long)(d0+dd)*NT + t0 + lane] = tile[lane][dd];
  }
}

// ======== chunked selective scan (B/C from dblT rows 64.. / 96.., dtu on the fly) ========
__global__ __launch_bounds__(64) void scan1_k(
  const float* __restrict__ deltaT, const float* __restrict__ xsT,
  const float* __restrict__ dblT, const float* __restrict__ A_log,
  float* __restrict__ hend, float* __restrict__ sumdt)
{
  int lane = threadIdx.x, half = lane >> 5, ln = lane & 31;
  int bi = blockIdx.x;
  int pair = bi >> 4, c = bi & (NC-1);
  int ch = pair*2 + half;
  int b = ch >> 10, d = ch & (DI-1);
  float An = -__expf(A_log[d*DS + ln]);
  long base = (long)b*LL + c*CL;
  const float* dtp = deltaT + (long)d*NT + base;
  const float* xsp = xsT + (long)d*NT + base;
  const float4* Bp = reinterpret_cast<const float4*>(dblT + (long)(64+ln)*NT + base);
  float h = 0.f, sdt = 0.f;
  for (int g = 0; g < CL/32; g++) {
    float dtv  = dtp[g*32 + ln];
    float dtuv = dtv * xsp[g*32 + ln];
    float Bv[32];
    #pragma unroll
    for (int q = 0; q < 8; q++) {
      float4 v = Bp[g*8+q];
      Bv[q*4+0]=v.x; Bv[q*4+1]=v.y; Bv[q*4+2]=v.z; Bv[q*4+3]=v.w;
    }
    float s = dtv;
    #pragma unroll
    for (int off = 16; off >= 1; off >>= 1) s += __shfl_xor(s, off, 32);
    sdt += s;
    float av[32], wv[32];
    #pragma unroll
    for (int tt = 0; tt < 32; tt++) {
      av[tt] = __expf(__shfl(dtv, tt, 32) * An);
      wv[tt] = __shfl(dtuv, tt, 32) * Bv[tt];
    }
    #pragma unroll
    for (int tt = 0; tt < 32; tt++) h = fmaf(av[tt], h, wv[tt]);
  }
  hend[((long)c*2048 + ch)*32 + ln] = h;
  if (ln == 0) sumdt[c*2048 + ch] = sdt;
}

__global__ __launch_bounds__(256) void scan2_k(
  float* __restrict__ hend, const float* __restrict__ sumdt,
  const float* __restrict__ A_log)
{
  int idx = blockIdx.x*256 + threadIdx.x;   // 0..65535
  int ch = idx >> 5, n = idx & 31;
  int d = ch & (DI-1);
  float An = -__expf(A_log[d*DS + n]);
  float H = 0.f;
  for (int c = 0; c < NC; c++) {
    long o = ((long)c*2048 + ch)*32 + n;
    float he = hend[o];
    float P = __expf(An * sumdt[c*2048 + ch]);
    hend[o] = H;
    H = P*H + he;
  }
}

__global__ __launch_bounds__(64) void scan3_k(
  const float* __restrict__ deltaT, const float* __restrict__ xsT,
  const float* __restrict__ dblT, const float* __restrict__ A_log,
  const float* __restrict__ hini, float* __restrict__ ygT)
{
  __shared__ float ys[2*32*33];
  int lane = threadIdx.x, half = lane >> 5, ln = lane & 31;
  int bi = blockIdx.x;
  int pair = bi >> 4, c = bi & (NC-1);
  int ch = pair*2 + half;
  int b = ch >> 10, d = ch & (DI-1);
  float An = -__expf(A_log[d*DS + ln]);
  long base = (long)b*LL + c*CL;
  const float* dtp = deltaT + (long)d*NT + base;
  const float* xsp = xsT + (long)d*NT + base;
  const float4* Bp = reinterpret_cast<const float4*>(dblT + (long)(64+ln)*NT + base);
  const float4* Cp = reinterpret_cast<const float4*>(dblT + (long)(96+ln)*NT + base);
  float* yp = ygT + (long)d*NT + base;
  float* lds = ys + half*(32*33);
  float h = hini[((long)c*2048 + ch)*32 + ln];
  for (int g = 0; g < CL/32; g++) {
    float dtv  = dtp[g*32 + ln];
    float dtuv = dtv * xsp[g*32 + ln];
    float Bv[32], Cv[32];
    #pragma unroll
    for (int q = 0; q < 8; q++) {
      float4 v = Bp[g*8+q];
      Bv[q*4+0]=v.x; Bv[q*4+1]=v.y; Bv[q*4+2]=v.z; Bv[q*4+3]=v.w;
      float4 u = Cp[g*8+q];
      Cv[q*4+0]=u.x; Cv[q*4+1]=u.y; Cv[q*4+2]=u.z; Cv[q*4+3]=u.w;
    }
    float av[32], wv[32];
    #pragma unroll
    for (int tt = 0; tt < 32; tt++) {
      av[tt] = __expf(__shfl(dtv, tt, 32) * An);
      wv[tt] = __shfl(dtuv, tt, 32) * Bv[tt];
    }
    #pragma unroll
    for (int tt = 0; tt < 32; tt++) {
      h = fmaf(av[tt], h, wv[tt]);
      lds[tt*33 + ln] = h * Cv[tt];
    }
    __syncthreads();
    float y = 0.f;
    #pragma unroll
    for (int k = 0; k < 32; k++) y += lds[ln*33 + k];
    yp[g*32 + ln] = y;
    __syncthreads();
  }
}

// -------- yg16[t][d] = bf16((ygT[d][t] + u*D) * silu(z)) --------
__global__ __launch_bounds__(256) void mulz_k(
    const float* __restrict__ ygT, const ushort* __restrict__ xs16,
    const float* __restrict__ xz, const float* __restrict__ Dp,
    ushort* __restrict__ yg16)
{
  __shared__ float tile[32][33];
  int d0 = blockIdx.x*32, t0 = blockIdx.y*32;
  int tx = threadIdx.x & 31, ty = threadIdx.x >> 5;
  #pragma unroll
  for (int k = 0; k < 4; k++)
    tile[ty+8*k][tx] = ygT[(long)(d0+ty+8*k)*NT + t0+tx];
  __syncthreads();
  #pragma unroll
  for (int k = 0; k < 4; k++) {
    long tok = t0+ty+8*k; int d = d0+tx;
    float u = b2f(xs16[tok*DI + d]);
    float z = xz[tok*2*DI + DI + d];
    yg16[tok*DI + d] = f2b((tile[tx][ty+8*k] + u*Dp[d]) * siluf_(z));
  }
}

// -------- combined = bf16(ssm*silu(ge) + xc*(1-gate)) --------
__global__ __launch_bounds__(256) void combine_k(
    const float* __restrict__ ssm, const float* __restrict__ gate,
    const float* __restrict__ xc, ushort* __restrict__ comb16)
{
  long i = (long)blockIdx.x*256 + threadIdx.x;
  int o = (int)(i & (DI-1));
  long tok = i >> 10;
  float gv = gate[tok*DM + (o>>1)];
  comb16[i] = f2b(ssm[i] * siluf_(gv) + xc[i] * (1.f - gv));
}

// -------- final LN over 512 of (pre + residual) --------
__global__ __launch_bounds__(256) void final_ln_k(
    const float* __restrict__ pre, const float* __restrict__ x,
    const float* __restrict__ g, const float* __restrict__ bt, float* __restrict__ out)
{
  int token = blockIdx.x;
  __shared__ float red[4];
  float v[2]; float sum = 0.f;
  #pragma unroll
  for (int i = 0; i < 2; i++) {
    int o = threadIdx.x + i*256;
    float t = pre[(long)token*DM+o] + x[(long)token*DM+o];
    v[i] = t; sum += t;
  }
  float mean = block_sum4(sum, red) * (1.f/DM);
  float vs = 0.f;
  #pragma unroll
  for (int i = 0; i < 2; i++) { float d = v[i]-mean; vs += d*d; }
  float var = block_sum4(vs, red) * (1.f/DM);
  float inv = rsqrtf(var + 1e-5f);
  #pragma unroll
  for (int i = 0; i < 2; i++) {
    int o = threadIdx.x + i*256;
    out[(long)token*DM + o] = (v[i]-mean)*inv*g[o] + bt[o];
  }
}

extern "C" void kernel_launch(void* const* d_in, const int* in_sizes, int n_in,
                              void* d_out, int out_size, void* d_ws, size_t ws_size,
                              hipStream_t stream)
{
  const float* x         = (const float*)d_in[0];
  const float* conv_w    = (const float*)d_in[1];
  const float* conv_b    = (const float*)d_in[2];
  const float* gate_w    = (const float*)d_in[3];
  const float* gate_b    = (const float*)d_in[4];
  const float* out_w     = (const float*)d_in[5];
  const float* out_b     = (const float*)d_in[6];
  const float* ln1_g     = (const float*)d_in[7];
  const float* ln1_b     = (const float*)d_in[8];
  const float* ln2_g     = (const float*)d_in[9];
  const float* ln2_b     = (const float*)d_in[10];
  const float* in_proj_w = (const float*)d_in[11];
  const float* ssm_conv_w= (const float*)d_in[12];
  const float* ssm_conv_b= (const float*)d_in[13];
  const float* x_proj_w  = (const float*)d_in[14];
  const float* dt_proj_w = (const float*)d_in[15];
  const float* dt_proj_b = (const float*)d_in[16];
  const float* A_log     = (const float*)d_in[17];
  const float* D_param   = (const float*)d_in[18];
  const float* out_proj_w= (const float*)d_in[19];

  float* ws     = (float*)d_ws;
  float* xz     = ws;                    // 8388608
  float* xc     = xz + 8388608;          // 4194304
  float* gate   = xc + 4194304;          // 2097152
  float* xsT    = gate + 2097152;        // 4194304
  float* R      = xsT + 4194304;         // 4194304 (16MB multi-use region)
  float* dblT   = R + 4194304;           // 524288
  float* deltaT = dblT + 524288;         // 4194304
  float* ygT    = deltaT + 4194304;      // 4194304

  // R region aliases (lifetimes disjoint):
  ushort* x16   = (ushort*)R;            // steps 1-4   (2097152 ush)
  ushort* xc16  = x16 + 2097152;         // steps 3-5   (4194304 ush)
  float*  dblP  = R;                     // steps 7-8   (KS*NT*128 = 4194304 f32)
  float*  hend  = R;                     // steps 10-12 (1048576 f32)
  float*  ssm   = R;                     // steps 14-15 (4194304 f32)
  float*  pre   = deltaT;                // steps 16-17 (deltaT dead after scan3)

  ushort* b16   = (ushort*)(ygT + 4194304);
  ushort* yg16  = b16;                   // 4194304 ush
  ushort* xs16  = yg16 + 4194304;        // 4194304 ush
  ushort* comb16= xs16;                  // reuse after mulz
  ushort* gate_wT = xs16 + 4194304;      // 262144
  ushort* in_wT   = gate_wT + 262144;    // 2097152
  ushort* xp_wT   = in_wT + 2097152;     // 131072
  ushort* dt_wT   = xp_wT + 131072;      // 65536
  ushort* op_wT   = dt_wT + 65536;       // 1048576
  ushort* ow_wT   = op_wT + 1048576;     // 524288
  float*  sumdt   = (float*)(ow_wT + 524288);  // 32768 f32
  float* outp   = (float*)d_out;

  convx_k<<<(NT*DM/4)/256, 256, 0, stream>>>(x, x16);                                      // 1
  wtall_k<<<4032, 256, 0, stream>>>(gate_w, in_proj_w, x_proj_w, dt_proj_w, out_proj_w, out_w,
                                    gate_wT, in_wT, xp_wT, dt_wT, op_wT, ow_wT);           // 2
  conv_ln_k<<<NT, 256, 0, stream>>>(x, conv_w, conv_b, ln2_g, ln2_b, xc, xc16);            // 3
  bgemm_k<<<dim3(DM/128, NT/128), 256, 0, stream>>>(x16, DM, gate_wT, gate_b, gate, NT, DM, DM, 1);       // 4
  bgemm_k<<<dim3(2*DI/128, NT/128), 256, 0, stream>>>(xc16, DI, in_wT, nullptr, xz, NT, 2*DI, DI, 0);     // 5
  ssm_conv2_k<<<dim3(DI/64, NT/64), 256, 0, stream>>>(xz, ssm_conv_w, ssm_conv_b, xs16, xsT);             // 6
  xproj_k<<<dim3(KS, NT/128), 256, 0, stream>>>(xs16, xp_wT, dblP);                        // 7
  dblred_k<<<dim3(NT/32, 128/32), 256, 0, stream>>>(dblP, dblT);                           // 8
  dtg_k<<<dim3(NT/64, DI/64), 256, 0, stream>>>(dblT, dt_wT, dt_proj_b, deltaT);           // 9
  scan1_k<<<1024*NC, 64, 0, stream>>>(deltaT, xsT, dblT, A_log, hend, sumdt);              // 10
  scan2_k<<<(2048*32)/256, 256, 0, stream>>>(hend, sumdt, A_log);                          // 11
  scan3_k<<<1024*NC, 64, 0, stream>>>(deltaT, xsT, dblT, A_log, hend, ygT);                // 12
  mulz_k<<<dim3(DI/32, NT/32), 256, 0, stream>>>(ygT, xs16, xz, D_param, yg16);            // 13
  bgemm_k<<<dim3(DI/128, NT/128), 256, 0, stream>>>(yg16, DI, op_wT, nullptr, ssm, NT, DI, DI, 0);        // 14
  combine_k<<<(NT*DI)/256, 256, 0, stream>>>(ssm, gate, xc, comb16);                       // 15
  bgemm_k<<<dim3(DM/128, NT/128), 256, 0, stream>>>(comb16, DI, ow_wT, out_b, pre, NT, DM, DI, 3);        // 16
  final_ln_k<<<NT, 256, 0, stream>>>(pre, x, ln1_g, ln1_b, outp);                          // 17
}

// Round 6
// 375.154 us; speedup vs baseline: 6.3995x; 1.0789x over previous
//
#include <hip/hip_runtime.h>
#include <cmath>

#define BB   2
#define LL   2048
#define DM   512
#define DI   1024
#define DS   32
#define DTR  64
#define NT   (BB*LL)   // 4096 tokens
#define NC   16        // chunks per sequence
#define CL   128       // chunk length (NC*CL == LL)
#define KS   8         // x_proj K-slices

typedef short bf16x8 __attribute__((ext_vector_type(8)));
typedef float f32x4  __attribute__((ext_vector_type(4)));

__device__ __forceinline__ float sigmoidf_(float x){ return 1.f/(1.f+__expf(-x)); }
__device__ __forceinline__ float siluf_(float x){ return x*sigmoidf_(x); }
__device__ __forceinline__ ushort f2b(float f){
  union { float f; unsigned u; } x; x.f = f;
  unsigned r = (x.u + 0x7FFFu + ((x.u >> 16) & 1u)) >> 16;
  return (ushort)r;
}
__device__ __forceinline__ float b2f(ushort v){
  union { unsigned u; float f; } x; x.u = ((unsigned)v) << 16; return x.f;
}

// block-wide sum over 256 threads (4 waves)
__device__ __forceinline__ float block_sum4(float v, float* red) {
  #pragma unroll
  for (int off = 32; off >= 1; off >>= 1) v += __shfl_xor(v, off, 64);
  int w = threadIdx.x >> 6;
  __syncthreads();
  if ((threadIdx.x & 63) == 0) red[w] = v;
  __syncthreads();
  return red[0] + red[1] + red[2] + red[3];
}

// -------- f32 -> bf16 elementwise (x), 4 elems/thread --------
__global__ __launch_bounds__(256) void convx_k(
    const float* __restrict__ in, ushort* __restrict__ out)
{
  int i = blockIdx.x*256 + threadIdx.x;
  float4 v = reinterpret_cast<const float4*>(in)[i];
  ushort4 o; o.x=f2b(v.x); o.y=f2b(v.y); o.z=f2b(v.z); o.w=f2b(v.w);
  reinterpret_cast<ushort4*>(out)[i] = o;
}

// -------- all weight transposes in ONE launch: W[K][N] f32 -> WT[N][K] bf16 --------
__global__ __launch_bounds__(256) void wtall_k(
  const float* __restrict__ s0, const float* __restrict__ s1, const float* __restrict__ s2,
  const float* __restrict__ s3, const float* __restrict__ s4, const float* __restrict__ s5,
  ushort* __restrict__ d0, ushort* __restrict__ d1, ushort* __restrict__ d2,
  ushort* __restrict__ d3, ushort* __restrict__ d4, ushort* __restrict__ d5)
{
  // jobs: gate(512,512) in(1024,2048) xp(1024,128) dt(64,1024) op(1024,1024) ow(1024,512)
  const int pre[7] = {0,256,2304,2432,2496,3520,4032};
  const int Ks[6] = {512,1024,1024,64,1024,1024};
  const int Ns[6] = {512,2048,128,1024,1024,512};
  int bid = blockIdx.x;
  int j = 0;
  while (bid >= pre[j+1]) j++;
  int rem = bid - pre[j];
  int gx = Ns[j] >> 5;
  int n0 = (rem % gx)*32, k0 = (rem / gx)*32;
  const float* W = j==0?s0: j==1?s1: j==2?s2: j==3?s3: j==4?s4: s5;
  ushort* WT     = j==0?d0: j==1?d1: j==2?d2: j==3?d3: j==4?d4: d5;
  int K = Ks[j], N = Ns[j];
  __shared__ float t[32][33];
  int tx = threadIdx.x & 31, ty = threadIdx.x >> 5;
  #pragma unroll
  for (int i = 0; i < 4; i++)
    t[ty+8*i][tx] = W[(long)(k0+ty+8*i)*N + n0+tx];
  __syncthreads();
  #pragma unroll
  for (int i = 0; i < 4; i++)
    WT[(long)(n0+ty+8*i)*K + k0+tx] = f2b(t[tx][ty+8*i]);
}

// -------- fused dwconv(k=3, chan-mult 2) + silu + LN over 1024 --------
__global__ __launch_bounds__(256) void conv_ln_k(
    const float* __restrict__ x, const float* __restrict__ cw, const float* __restrict__ cb,
    const float* __restrict__ g, const float* __restrict__ bt,
    float* __restrict__ xc, ushort* __restrict__ xc16)
{
  int token = blockIdx.x;
  int l = token & (LL-1);
  __shared__ float red[4];
  float v[4]; float sum = 0.f;
  #pragma unroll
  for (int i = 0; i < 4; i++) {
    int o = threadIdx.x + i*256;
    int c = o >> 1;
    const float* xp = x + (long)token*DM + c;
    float s = cb[o];
    if (l >= 1)    s += xp[-DM] * cw[o*3+0];
                   s += xp[0]   * cw[o*3+1];
    if (l < LL-1)  s += xp[DM]  * cw[o*3+2];
    float t = siluf_(s);
    v[i] = t; sum += t;
  }
  float mean = block_sum4(sum, red) * (1.f/DI);
  float vs = 0.f;
  #pragma unroll
  for (int i = 0; i < 4; i++) { float d = v[i]-mean; vs += d*d; }
  float var = block_sum4(vs, red) * (1.f/DI);
  float inv = rsqrtf(var + 1e-5f);
  #pragma unroll
  for (int i = 0; i < 4; i++) {
    int o = threadIdx.x + i*256;
    float r = (v[i]-mean)*inv*g[o] + bt[o];
    xc[(long)token*DI + o] = r;
    xc16[(long)token*DI + o] = f2b(r);
  }
}

// -------- bf16 MFMA GEMM: 128x128 tile, BK=32, 4 waves --------
// mode: 0=plain, 1=sigmoid+bias, 3=bias
__global__ __launch_bounds__(256) void bgemm_k(
    const ushort* __restrict__ A, int lda,
    const ushort* __restrict__ WT,
    const float* __restrict__ bias,
    float* __restrict__ C,
    int M, int N, int K, int mode)
{
  __shared__ ushort As[128*32];
  __shared__ ushort Bs[128*32];
  int tid = threadIdx.x;
  int wid = tid >> 6, lane = tid & 63;
  int wr = wid >> 1, wc = wid & 1;
  int m0 = blockIdx.y*128, n0 = blockIdx.x*128;
  int lr = lane & 15, kq = lane >> 4;
  f32x4 acc[4][4] = {};
  for (int k0 = 0; k0 < K; k0 += 32) {
    #pragma unroll
    for (int it = 0; it < 2; it++) {
      int idx = tid + it*256;
      int row = idx >> 2, seg = idx & 3;
      uint4 va = *reinterpret_cast<const uint4*>(A + (long)(m0+row)*lda + k0 + seg*8);
      uint4 vb = *reinterpret_cast<const uint4*>(WT + (long)(n0+row)*K + k0 + seg*8);
      int off = (row*64 + seg*16) ^ ((row&7)<<4);
      *reinterpret_cast<uint4*>((char*)As + off) = va;
      *reinterpret_cast<uint4*>((char*)Bs + off) = vb;
    }
    __syncthreads();
    bf16x8 af[4], bg[4];
    #pragma unroll
    for (int i = 0; i < 4; i++) {
      int row = wr*64 + i*16 + lr;
      af[i] = *reinterpret_cast<const bf16x8*>((char*)As + ((row*64 + kq*16) ^ ((row&7)<<4)));
      int col = wc*64 + i*16 + lr;
      bg[i] = *reinterpret_cast<const bf16x8*>((char*)Bs + ((col*64 + kq*16) ^ ((col&7)<<4)));
    }
    #pragma unroll
    for (int i = 0; i < 4; i++)
      #pragma unroll
      for (int j = 0; j < 4; j++)
        acc[i][j] = __builtin_amdgcn_mfma_f32_16x16x32_bf16(af[i], bg[j], acc[i][j], 0, 0, 0);
    __syncthreads();
  }
  #pragma unroll
  for (int i = 0; i < 4; i++) {
    #pragma unroll
    for (int j = 0; j < 4; j++) {
      #pragma unroll
      for (int r = 0; r < 4; r++) {
        int m = m0 + wr*64 + i*16 + kq*4 + r;
        int n = n0 + wc*64 + j*16 + lr;
        float v = acc[i][j][r];
        long o = (long)m*N + n;
        if (mode == 0)      C[o] = v;
        else if (mode == 1) C[o] = sigmoidf_(v + bias[n]);
        else                C[o] = v + bias[n];
      }
    }
  }
}

// -------- x_proj split-K: partial[ks][t][n] over K-slice of 128 --------
__global__ __launch_bounds__(256) void xproj_k(
    const ushort* __restrict__ A,      // xs16 [NT][DI]
    const ushort* __restrict__ WT,     // xp_wT [128][DI]
    float* __restrict__ P)             // dblP [KS][NT][128]
{
  __shared__ ushort As[128*32];
  __shared__ ushort Bs[128*32];
  int tid = threadIdx.x;
  int wid = tid >> 6, lane = tid & 63;
  int wr = wid >> 1, wc = wid & 1;
  int m0 = blockIdx.y*128;
  int ks = blockIdx.x;
  int lr = lane & 15, kq = lane >> 4;
  f32x4 acc[4][4] = {};
  for (int k0 = ks*128; k0 < ks*128 + 128; k0 += 32) {
    #pragma unroll
    for (int it = 0; it < 2; it++) {
      int idx = tid + it*256;
      int row = idx >> 2, seg = idx & 3;
      uint4 va = *reinterpret_cast<const uint4*>(A + (long)(m0+row)*DI + k0 + seg*8);
      uint4 vb = *reinterpret_cast<const uint4*>(WT + (long)row*DI + k0 + seg*8);
      int off = (row*64 + seg*16) ^ ((row&7)<<4);
      *reinterpret_cast<uint4*>((char*)As + off) = va;
      *reinterpret_cast<uint4*>((char*)Bs + off) = vb;
    }
    __syncthreads();
    bf16x8 af[4], bg[4];
    #pragma unroll
    for (int i = 0; i < 4; i++) {
      int row = wr*64 + i*16 + lr;
      af[i] = *reinterpret_cast<const bf16x8*>((char*)As + ((row*64 + kq*16) ^ ((row&7)<<4)));
      int col = wc*64 + i*16 + lr;
      bg[i] = *reinterpret_cast<const bf16x8*>((char*)Bs + ((col*64 + kq*16) ^ ((col&7)<<4)));
    }
    #pragma unroll
    for (int i = 0; i < 4; i++)
      #pragma unroll
      for (int j = 0; j < 4; j++)
        acc[i][j] = __builtin_amdgcn_mfma_f32_16x16x32_bf16(af[i], bg[j], acc[i][j], 0, 0, 0);
    __syncthreads();
  }
  float* C = P + (long)ks*NT*128;
  #pragma unroll
  for (int i = 0; i < 4; i++)
    #pragma unroll
    for (int j = 0; j < 4; j++)
      #pragma unroll
      for (int r = 0; r < 4; r++) {
        int m = m0 + wr*64 + i*16 + kq*4 + r;
        int n = wc*64 + j*16 + lr;
        C[(long)m*128 + n] = acc[i][j][r];
      }
}

// -------- reduce KS partials + transpose -> dblT[128][NT] --------
__global__ __launch_bounds__(256) void dblred_k(
    const float* __restrict__ P, float* __restrict__ dblT)
{
  __shared__ float t[32][33];
  int t0 = blockIdx.x*32, n0 = blockIdx.y*32;
  int tx = threadIdx.x & 31, ty = threadIdx.x >> 5;
  #pragma unroll
  for (int i = 0; i < 4; i++) {
    float s = 0.f;
    long o = (long)(t0+ty+8*i)*128 + n0+tx;
    #pragma unroll
    for (int sl = 0; sl < KS; sl++) s += P[(long)sl*NT*128 + o];
    t[ty+8*i][tx] = s;
  }
  __syncthreads();
  #pragma unroll
  for (int i = 0; i < 4; i++)
    dblT[(long)(n0+ty+8*i)*NT + t0+tx] = t[tx][ty+8*i];
}

// -------- dt_proj fused: deltaT[d][t] = softplus(dt_wT[d][:] @ dblT[:64][t] + b[d]) --------
__global__ __launch_bounds__(256) void dtg_k(
    const float* __restrict__ dblT, const ushort* __restrict__ dtw,
    const float* __restrict__ bias, float* __restrict__ deltaT)
{
  __shared__ ushort Asub[64*72];   // [d][k] padded
  __shared__ float Bsub[64*65];    // [k][t] padded
  int tid = threadIdx.x;
  int d0 = blockIdx.y*64, t0 = blockIdx.x*64;
  {
    int row = tid >> 2, seg = tid & 3;
    const uint4* src = reinterpret_cast<const uint4*>(dtw + (long)(d0+row)*64 + seg*16);
    uint4* dst = reinterpret_cast<uint4*>(Asub + row*72 + seg*16);
    dst[0] = src[0]; dst[1] = src[1];
  }
  {
    int row = tid >> 2, seg = tid & 3;
    const float4* src = reinterpret_cast<const float4*>(dblT + (long)row*NT + t0 + seg*16);
    float* dst = Bsub + row*65 + seg*16;
    #pragma unroll
    for (int q = 0; q < 4; q++) {
      float4 v = src[q];
      dst[q*4+0]=v.x; dst[q*4+1]=v.y; dst[q*4+2]=v.z; dst[q*4+3]=v.w;
    }
  }
  __syncthreads();
  int wid = tid >> 6, lane = tid & 63, lr = lane & 15, kq = lane >> 4;
  f32x4 acc[4] = {};
  #pragma unroll
  for (int kstep = 0; kstep < 2; kstep++) {
    bf16x8 af = *reinterpret_cast<const bf16x8*>(Asub + (wid*16+lr)*72 + kstep*32 + kq*8);
    #pragma unroll
    for (int j = 0; j < 4; j++) {
      bf16x8 bg;
      #pragma unroll
      for (int e = 0; e < 8; e++)
        bg[e] = (short)f2b(Bsub[(kstep*32 + kq*8 + e)*65 + j*16 + lr]);
      acc[j] = __builtin_amdgcn_mfma_f32_16x16x32_bf16(af, bg, acc[j], 0, 0, 0);
    }
  }
  #pragma unroll
  for (int j = 0; j < 4; j++)
    #pragma unroll
    for (int r = 0; r < 4; r++) {
      int d = d0 + wid*16 + kq*4 + r;
      float v = acc[j][r] + bias[d];
      v = fmaxf(v, 0.f) + log1pf(__expf(-fabsf(v)));
      deltaT[(long)d*NT + t0 + j*16 + lr] = v;
    }
}

// -------- tiled causal dwconv(k=4) + silu: writes xs16 (t-major) + xsT (d-major) --------
__global__ __launch_bounds__(256) void ssm_conv2_k(
    const float* __restrict__ xz, const float* __restrict__ w4,
    const float* __restrict__ bias, ushort* __restrict__ xs16,
    float* __restrict__ xsT)
{
  __shared__ float tile[64][65];
  int d0 = blockIdx.x*64, t0 = blockIdx.y*64;
  int wv = threadIdx.x >> 6, lane = threadIdx.x & 63;
  int d = d0 + lane;
  float w0 = w4[d*4+0], w1 = w4[d*4+1], w2 = w4[d*4+2], w3 = w4[d*4+3];
  float bs = bias[d];
  int tstart = t0 + wv*16;
  int lstart = tstart & (LL-1);
  const float* xp = xz + (long)tstart*2*DI + d;
  float x0 = (lstart >= 3) ? xp[-3*2*DI] : 0.f;
  float x1 = (lstart >= 2) ? xp[-2*2*DI] : 0.f;
  float x2 = (lstart >= 1) ? xp[-1*2*DI] : 0.f;
  #pragma unroll
  for (int i = 0; i < 16; i++) {
    float x3 = xp[(long)i*2*DI];
    float s = bs + w0*x0 + w1*x1 + w2*x2 + w3*x3;
    tile[wv*16+i][lane] = siluf_(s);
    x0 = x1; x1 = x2; x2 = x3;
  }
  __syncthreads();
  #pragma unroll
  for (int i = 0; i < 16; i++) {
    int tt = wv + i*4;
    xs16[(long)(t0+tt)*DI + d0 + lane] = f2b(tile[tt][lane]);
  }
  #pragma unroll
  for (int i = 0; i < 16; i++) {
    int dd = wv + i*4;
    xsT[(long)(d0+dd)*NT + t0 + lane] = tile[lane][dd];
  }
}

// ======== chunked selective scan ========
// merged local scan: from h=0, writes y0 (ygT), hend, sumdt in ONE pass
__global__ __launch_bounds__(64) void scanA_k(
  const float* __restrict__ deltaT, const float* __restrict__ xsT,
  const float* __restrict__ dblT, const float* __restrict__ A_log,
  float* __restrict__ ygT, float* __restrict__ hend, float* __restrict__ sumdt)
{
  __shared__ float ys[2*32*33];
  int lane = threadIdx.x, half = lane >> 5, ln = lane & 31;
  int bi = blockIdx.x;
  int pair = bi >> 4, c = bi & (NC-1);
  int ch = pair*2 + half;
  int b = ch >> 10, d = ch & (DI-1);
  float An = -__expf(A_log[d*DS + ln]);
  long base = (long)b*LL + c*CL;
  const float* dtp = deltaT + (long)d*NT + base;
  const float* xsp = xsT + (long)d*NT + base;
  const float4* Bp = reinterpret_cast<const float4*>(dblT + (long)(64+ln)*NT + base);
  const float4* Cp = reinterpret_cast<const float4*>(dblT + (long)(96+ln)*NT + base);
  float* yp = ygT + (long)d*NT + base;
  float* lds = ys + half*(32*33);
  float h = 0.f, sdt = 0.f;
  for (int g = 0; g < CL/32; g++) {
    float dtv  = dtp[g*32 + ln];
    float dtuv = dtv * xsp[g*32 + ln];
    float Bv[32], Cv[32];
    #pragma unroll
    for (int q = 0; q < 8; q++) {
      float4 v = Bp[g*8+q];
      Bv[q*4+0]=v.x; Bv[q*4+1]=v.y; Bv[q*4+2]=v.z; Bv[q*4+3]=v.w;
      float4 u = Cp[g*8+q];
      Cv[q*4+0]=u.x; Cv[q*4+1]=u.y; Cv[q*4+2]=u.z; Cv[q*4+3]=u.w;
    }
    float s = dtv;
    #pragma unroll
    for (int off = 16; off >= 1; off >>= 1) s += __shfl_xor(s, off, 32);
    sdt += s;
    // 8-t sub-blocks: materialize av/wv (exp + shfl) BEFORE the serial FMA chain
    #pragma unroll
    for (int sub = 0; sub < 4; sub++) {
      float av[8], wv[8];
      #pragma unroll
      for (int k = 0; k < 8; k++) {
        int tt = sub*8 + k;
        av[k] = __expf(__shfl(dtv, tt, 32) * An);
        wv[k] = __shfl(dtuv, tt, 32) * Bv[tt];
      }
      __builtin_amdgcn_sched_barrier(0);   // keep exp/shfl off the h-chain
      #pragma unroll
      for (int k = 0; k < 8; k++) {
        int tt = sub*8 + k;
        h = fmaf(av[k], h, wv[k]);
        lds[tt*33 + ln] = h * Cv[tt];
      }
    }
    __syncthreads();
    float y = 0.f;
    #pragma unroll
    for (int k = 0; k < 32; k++) y += lds[ln*33 + k];
    yp[g*32 + ln] = y;
    __syncthreads();
  }
  hend[((long)c*2048 + ch)*32 + ln] = h;
  if (ln == 0) sumdt[c*2048 + ch] = sdt;
}

// sequential chunk combine; hend[c] overwritten with initial state S_c
__global__ __launch_bounds__(256) void scan2_k(
  float* __restrict__ hend, const float* __restrict__ sumdt,
  const float* __restrict__ A_log)
{
  int idx = blockIdx.x*256 + threadIdx.x;   // 0..65535
  int ch = idx >> 5, n = idx & 31;
  int d = ch & (DI-1);
  float An = -__expf(A_log[d*DS + n]);
  float H = 0.f;
  for (int c = 0; c < NC; c++) {
    long o = ((long)c*2048 + ch)*32 + n;
    float he = hend[o];
    float P = __expf(An * sumdt[c*2048 + ch]);
    hend[o] = H;
    H = P*H + he;
  }
}

// h_init correction: y[d][t] += sum_n C_t[n]*exp(A_n*cumdt_t)*hini[n]
// one wave per (channel, chunk); chunks 1..NC-1 (chunk 0 has hini=0)
__global__ __launch_bounds__(64) void fix_k(
  const float* __restrict__ deltaT, const float* __restrict__ dblT,
  const float* __restrict__ A_log, const float* __restrict__ hini,
  float* __restrict__ ygT)
{
  int lane = threadIdx.x;
  int bi = blockIdx.x;               // 2048 * (NC-1)
  int ch = bi / (NC-1);
  int c  = 1 + bi % (NC-1);
  int b = ch >> 10, d = ch & (DI-1);
  long base = (long)b*LL + c*CL;
  const float* dtp = deltaT + (long)d*NT + base;
  float pA = dtp[lane];
  float pB = dtp[64 + lane];
  // inclusive prefix over 128 t (two 64-halves)
  #pragma unroll
  for (int off = 1; off < 64; off <<= 1) {
    float ta = __shfl(pA, lane-off, 64);
    float tb = __shfl(pB, lane-off, 64);
    if (lane >= off) { pA += ta; pB += tb; }
  }
  pB += __shfl(pA, 63, 64);
  float hv   = hini[((long)c*2048 + ch)*32 + (lane & 31)];
  float Aown = -__expf(A_log[d*DS + (lane & 31)]);
  const float* Cbase = dblT + (long)96*NT + base;
  float yA = 0.f, yB = 0.f;
  #pragma unroll 8
  for (int n = 0; n < 32; n++) {
    float An = __shfl(Aown, n, 32);
    float hn = __shfl(hv, n, 32);
    const float* Cr = Cbase + (long)n*NT;
    yA = fmaf(Cr[lane]      * __expf(An*pA), hn, yA);
    yB = fmaf(Cr[64 + lane] * __expf(An*pB), hn, yB);
  }
  float* yp = ygT + (long)d*NT + base;
  yp[lane]      += yA;
  yp[64 + lane] += yB;
}

// -------- yg16[t][d] = bf16((ygT[d][t] + u*D) * silu(z)) --------
__global__ __launch_bounds__(256) void mulz_k(
    const float* __restrict__ ygT, const ushort* __restrict__ xs16,
    const float* __restrict__ xz, const float* __restrict__ Dp,
    ushort* __restrict__ yg16)
{
  __shared__ float tile[32][33];
  int d0 = blockIdx.x*32, t0 = blockIdx.y*32;
  int tx = threadIdx.x & 31, ty = threadIdx.x >> 5;
  #pragma unroll
  for (int k = 0; k < 4; k++)
    tile[ty+8*k][tx] = ygT[(long)(d0+ty+8*k)*NT + t0+tx];
  __syncthreads();
  #pragma unroll
  for (int k = 0; k < 4; k++) {
    long tok = t0+ty+8*k; int d = d0+tx;
    float u = b2f(xs16[tok*DI + d]);
    float z = xz[tok*2*DI + DI + d];
    yg16[tok*DI + d] = f2b((tile[tx][ty+8*k] + u*Dp[d]) * siluf_(z));
  }
}

// -------- combined = bf16(ssm*silu(ge) + xc*(1-gate)) --------
__global__ __launch_bounds__(256) void combine_k(
    const float* __restrict__ ssm, const float* __restrict__ gate,
    const float* __restrict__ xc, ushort* __restrict__ comb16)
{
  long i = (long)blockIdx.x*256 + threadIdx.x;
  int o = (int)(i & (DI-1));
  long tok = i >> 10;
  float gv = gate[tok*DM + (o>>1)];
  comb16[i] = f2b(ssm[i] * siluf_(gv) + xc[i] * (1.f - gv));
}

// -------- final LN over 512 of (pre + residual) --------
__global__ __launch_bounds__(256) void final_ln_k(
    const float* __restrict__ pre, const float* __restrict__ x,
    const float* __restrict__ g, const float* __restrict__ bt, float* __restrict__ out)
{
  int token = blockIdx.x;
  __shared__ float red[4];
  float v[2]; float sum = 0.f;
  #pragma unroll
  for (int i = 0; i < 2; i++) {
    int o = threadIdx.x + i*256;
    float t = pre[(long)token*DM+o] + x[(long)token*DM+o];
    v[i] = t; sum += t;
  }
  float mean = block_sum4(sum, red) * (1.f/DM);
  float vs = 0.f;
  #pragma unroll
  for (int i = 0; i < 2; i++) { float d = v[i]-mean; vs += d*d; }
  float var = block_sum4(vs, red) * (1.f/DM);
  float inv = rsqrtf(var + 1e-5f);
  #pragma unroll
  for (int i = 0; i < 2; i++) {
    int o = threadIdx.x + i*256;
    out[(long)token*DM + o] = (v[i]-mean)*inv*g[o] + bt[o];
  }
}

extern "C" void kernel_launch(void* const* d_in, const int* in_sizes, int n_in,
                              void* d_out, int out_size, void* d_ws, size_t ws_size,
                              hipStream_t stream)
{
  const float* x         = (const float*)d_in[0];
  const float* conv_w    = (const float*)d_in[1];
  const float* conv_b    = (const float*)d_in[2];
  const float* gate_w    = (const float*)d_in[3];
  const float* gate_b    = (const float*)d_in[4];
  const float* out_w     = (const float*)d_in[5];
  const float* out_b     = (const float*)d_in[6];
  const float* ln1_g     = (const float*)d_in[7];
  const float* ln1_b     = (const float*)d_in[8];
  const float* ln2_g     = (const float*)d_in[9];
  const float* ln2_b     = (const float*)d_in[10];
  const float* in_proj_w = (const float*)d_in[11];
  const float* ssm_conv_w= (const float*)d_in[12];
  const float* ssm_conv_b= (const float*)d_in[13];
  const float* x_proj_w  = (const float*)d_in[14];
  const float* dt_proj_w = (const float*)d_in[15];
  const float* dt_proj_b = (const float*)d_in[16];
  const float* A_log     = (const float*)d_in[17];
  const float* D_param   = (const float*)d_in[18];
  const float* out_proj_w= (const float*)d_in[19];

  float* ws     = (float*)d_ws;
  float* xz     = ws;                    // 8388608
  float* xc     = xz + 8388608;          // 4194304
  float* gate   = xc + 4194304;          // 2097152
  float* xsT    = gate + 2097152;        // 4194304
  float* R      = xsT + 4194304;         // 4194304 (16MB multi-use region)
  float* dblT   = R + 4194304;           // 524288
  float* deltaT = dblT + 524288;         // 4194304
  float* ygT    = deltaT + 4194304;      // 4194304

  // R region aliases (lifetimes disjoint):
  ushort* x16   = (ushort*)R;            // steps 1-4   (2097152 ush)
  ushort* xc16  = x16 + 2097152;         // steps 3-5   (4194304 ush)
  float*  dblP  = R;                     // steps 7-8   (KS*NT*128 = 4194304 f32)
  float*  hend  = R;                     // steps 10-12 (1048576 f32)
  float*  ssm   = R;                     // steps 14-15 (4194304 f32)
  float*  pre   = deltaT;                // steps 16-17 (deltaT dead after fix)

  ushort* b16   = (ushort*)(ygT + 4194304);
  ushort* yg16  = b16;                   // 4194304 ush
  ushort* xs16  = yg16 + 4194304;        // 4194304 ush
  ushort* comb16= xs16;                  // reuse after mulz
  ushort* gate_wT = xs16 + 4194304;      // 262144
  ushort* in_wT   = gate_wT + 262144;    // 2097152
  ushort* xp_wT   = in_wT + 2097152;     // 131072
  ushort* dt_wT   = xp_wT + 131072;      // 65536
  ushort* op_wT   = dt_wT + 65536;       // 1048576
  ushort* ow_wT   = op_wT + 1048576;     // 524288
  float*  sumdt   = (float*)(ow_wT + 524288);  // 32768 f32
  float* outp   = (float*)d_out;

  convx_k<<<(NT*DM/4)/256, 256, 0, stream>>>(x, x16);                                      // 1
  wtall_k<<<4032, 256, 0, stream>>>(gate_w, in_proj_w, x_proj_w, dt_proj_w, out_proj_w, out_w,
                                    gate_wT, in_wT, xp_wT, dt_wT, op_wT, ow_wT);           // 2
  conv_ln_k<<<NT, 256, 0, stream>>>(x, conv_w, conv_b, ln2_g, ln2_b, xc, xc16);            // 3
  bgemm_k<<<dim3(DM/128, NT/128), 256, 0, stream>>>(x16, DM, gate_wT, gate_b, gate, NT, DM, DM, 1);       // 4
  bgemm_k<<<dim3(2*DI/128, NT/128), 256, 0, stream>>>(xc16, DI, in_wT, nullptr, xz, NT, 2*DI, DI, 0);     // 5
  ssm_conv2_k<<<dim3(DI/64, NT/64), 256, 0, stream>>>(xz, ssm_conv_w, ssm_conv_b, xs16, xsT);             // 6
  xproj_k<<<dim3(KS, NT/128), 256, 0, stream>>>(xs16, xp_wT, dblP);                        // 7
  dblred_k<<<dim3(NT/32, 128/32), 256, 0, stream>>>(dblP, dblT);                           // 8
  dtg_k<<<dim3(NT/64, DI/64), 256, 0, stream>>>(dblT, dt_wT, dt_proj_b, deltaT);           // 9
  scanA_k<<<1024*NC, 64, 0, stream>>>(deltaT, xsT, dblT, A_log, ygT, hend, sumdt);         // 10
  scan2_k<<<(2048*32)/256, 256, 0, stream>>>(hend, sumdt, A_log);                          // 11
  fix_k<<<2048*(NC-1), 64, 0, stream>>>(deltaT, dblT, A_log, hend, ygT);                   // 12
  mulz_k<<<dim3(DI/32, NT/32), 256, 0, stream>>>(ygT, xs16, xz, D_param, yg16);            // 13
  bgemm_k<<<dim3(DI/128, NT/128), 256, 0, stream>>>(yg16, DI, op_wT, nullptr, ssm, NT, DI, DI, 0);        // 14
  combine_k<<<(NT*DI)/256, 256, 0, stream>>>(ssm, gate, xc, comb16);                       // 15
  bgemm_k<<<dim3(DM/128, NT/128), 256, 0, stream>>>(comb16, DI, ow_wT, out_b, pre, NT, DM, DI, 3);        // 16
  final_ln_k<<<NT, 256, 0, stream>>>(pre, x, ln1_g, ln1_b, outp);                          // 17
}

// Round 7
// 373.721 us; speedup vs baseline: 6.4241x; 1.0038x over previous
//
#include <hip/hip_runtime.h>
#include <cmath>

#define BB   2
#define LL   2048
#define DM   512
#define DI   1024
#define DS   32
#define DTR  64
#define NT   (BB*LL)   // 4096 tokens
#define NC   16        // chunks per sequence
#define CL   128       // chunk length (NC*CL == LL)
#define KS   8         // x_proj K-slices

typedef short bf16x8 __attribute__((ext_vector_type(8)));
typedef float f32x4  __attribute__((ext_vector_type(4)));

__device__ __forceinline__ float sigmoidf_(float x){ return 1.f/(1.f+__expf(-x)); }
__device__ __forceinline__ float siluf_(float x){ return x*sigmoidf_(x); }
__device__ __forceinline__ ushort f2b(float f){
  union { float f; unsigned u; } x; x.f = f;
  unsigned r = (x.u + 0x7FFFu + ((x.u >> 16) & 1u)) >> 16;
  return (ushort)r;
}
__device__ __forceinline__ float b2f(ushort v){
  union { unsigned u; float f; } x; x.u = ((unsigned)v) << 16; return x.f;
}

// block-wide sum over 256 threads (4 waves)
__device__ __forceinline__ float block_sum4(float v, float* red) {
  #pragma unroll
  for (int off = 32; off >= 1; off >>= 1) v += __shfl_xor(v, off, 64);
  int w = threadIdx.x >> 6;
  __syncthreads();
  if ((threadIdx.x & 63) == 0) red[w] = v;
  __syncthreads();
  return red[0] + red[1] + red[2] + red[3];
}

// -------- f32 -> bf16 elementwise (x), 4 elems/thread --------
__global__ __launch_bounds__(256) void convx_k(
    const float* __restrict__ in, ushort* __restrict__ out)
{
  int i = blockIdx.x*256 + threadIdx.x;
  float4 v = reinterpret_cast<const float4*>(in)[i];
  ushort4 o; o.x=f2b(v.x); o.y=f2b(v.y); o.z=f2b(v.z); o.w=f2b(v.w);
  reinterpret_cast<ushort4*>(out)[i] = o;
}

// -------- all weight transposes in ONE launch: W[K][N] f32 -> WT[N][K] bf16 --------
__global__ __launch_bounds__(256) void wtall_k(
  const float* __restrict__ s0, const float* __restrict__ s1, const float* __restrict__ s2,
  const float* __restrict__ s3, const float* __restrict__ s4, const float* __restrict__ s5,
  ushort* __restrict__ d0, ushort* __restrict__ d1, ushort* __restrict__ d2,
  ushort* __restrict__ d3, ushort* __restrict__ d4, ushort* __restrict__ d5)
{
  // jobs: gate(512,512) in(1024,2048) xp(1024,128) dt(64,1024) op(1024,1024) ow(1024,512)
  const int pre[7] = {0,256,2304,2432,2496,3520,4032};
  const int Ks[6] = {512,1024,1024,64,1024,1024};
  const int Ns[6] = {512,2048,128,1024,1024,512};
  int bid = blockIdx.x;
  int j = 0;
  while (bid >= pre[j+1]) j++;
  int rem = bid - pre[j];
  int gx = Ns[j] >> 5;
  int n0 = (rem % gx)*32, k0 = (rem / gx)*32;
  const float* W = j==0?s0: j==1?s1: j==2?s2: j==3?s3: j==4?s4: s5;
  ushort* WT     = j==0?d0: j==1?d1: j==2?d2: j==3?d3: j==4?d4: d5;
  int K = Ks[j], N = Ns[j];
  __shared__ float t[32][33];
  int tx = threadIdx.x & 31, ty = threadIdx.x >> 5;
  #pragma unroll
  for (int i = 0; i < 4; i++)
    t[ty+8*i][tx] = W[(long)(k0+ty+8*i)*N + n0+tx];
  __syncthreads();
  #pragma unroll
  for (int i = 0; i < 4; i++)
    WT[(long)(n0+ty+8*i)*K + k0+tx] = f2b(t[tx][ty+8*i]);
}

// -------- fused dwconv(k=3, chan-mult 2) + silu + LN over 1024 --------
__global__ __launch_bounds__(256) void conv_ln_k(
    const float* __restrict__ x, const float* __restrict__ cw, const float* __restrict__ cb,
    const float* __restrict__ g, const float* __restrict__ bt,
    float* __restrict__ xc, ushort* __restrict__ xc16)
{
  int token = blockIdx.x;
  int l = token & (LL-1);
  __shared__ float red[4];
  float v[4]; float sum = 0.f;
  #pragma unroll
  for (int i = 0; i < 4; i++) {
    int o = threadIdx.x + i*256;
    int c = o >> 1;
    const float* xp = x + (long)token*DM + c;
    float s = cb[o];
    if (l >= 1)    s += xp[-DM] * cw[o*3+0];
                   s += xp[0]   * cw[o*3+1];
    if (l < LL-1)  s += xp[DM]  * cw[o*3+2];
    float t = siluf_(s);
    v[i] = t; sum += t;
  }
  float mean = block_sum4(sum, red) * (1.f/DI);
  float vs = 0.f;
  #pragma unroll
  for (int i = 0; i < 4; i++) { float d = v[i]-mean; vs += d*d; }
  float var = block_sum4(vs, red) * (1.f/DI);
  float inv = rsqrtf(var + 1e-5f);
  #pragma unroll
  for (int i = 0; i < 4; i++) {
    int o = threadIdx.x + i*256;
    float r = (v[i]-mean)*inv*g[o] + bt[o];
    xc[(long)token*DI + o] = r;
    xc16[(long)token*DI + o] = f2b(r);
  }
}

// -------- bf16 MFMA GEMM: 128x128 tile, BK=32, 4 waves --------
// mode: 0=plain, 1=sigmoid+bias, 3=bias
__global__ __launch_bounds__(256) void bgemm_k(
    const ushort* __restrict__ A, int lda,
    const ushort* __restrict__ WT,
    const float* __restrict__ bias,
    float* __restrict__ C,
    int M, int N, int K, int mode)
{
  __shared__ ushort As[128*32];
  __shared__ ushort Bs[128*32];
  int tid = threadIdx.x;
  int wid = tid >> 6, lane = tid & 63;
  int wr = wid >> 1, wc = wid & 1;
  int m0 = blockIdx.y*128, n0 = blockIdx.x*128;
  int lr = lane & 15, kq = lane >> 4;
  f32x4 acc[4][4] = {};
  for (int k0 = 0; k0 < K; k0 += 32) {
    #pragma unroll
    for (int it = 0; it < 2; it++) {
      int idx = tid + it*256;
      int row = idx >> 2, seg = idx & 3;
      uint4 va = *reinterpret_cast<const uint4*>(A + (long)(m0+row)*lda + k0 + seg*8);
      uint4 vb = *reinterpret_cast<const uint4*>(WT + (long)(n0+row)*K + k0 + seg*8);
      int off = (row*64 + seg*16) ^ ((row&7)<<4);
      *reinterpret_cast<uint4*>((char*)As + off) = va;
      *reinterpret_cast<uint4*>((char*)Bs + off) = vb;
    }
    __syncthreads();
    bf16x8 af[4], bg[4];
    #pragma unroll
    for (int i = 0; i < 4; i++) {
      int row = wr*64 + i*16 + lr;
      af[i] = *reinterpret_cast<const bf16x8*>((char*)As + ((row*64 + kq*16) ^ ((row&7)<<4)));
      int col = wc*64 + i*16 + lr;
      bg[i] = *reinterpret_cast<const bf16x8*>((char*)Bs + ((col*64 + kq*16) ^ ((col&7)<<4)));
    }
    #pragma unroll
    for (int i = 0; i < 4; i++)
      #pragma unroll
      for (int j = 0; j < 4; j++)
        acc[i][j] = __builtin_amdgcn_mfma_f32_16x16x32_bf16(af[i], bg[j], acc[i][j], 0, 0, 0);
    __syncthreads();
  }
  #pragma unroll
  for (int i = 0; i < 4; i++) {
    #pragma unroll
    for (int j = 0; j < 4; j++) {
      #pragma unroll
      for (int r = 0; r < 4; r++) {
        int m = m0 + wr*64 + i*16 + kq*4 + r;
        int n = n0 + wc*64 + j*16 + lr;
        float v = acc[i][j][r];
        long o = (long)m*N + n;
        if (mode == 0)      C[o] = v;
        else if (mode == 1) C[o] = sigmoidf_(v + bias[n]);
        else                C[o] = v + bias[n];
      }
    }
  }
}

// -------- x_proj split-K: partial[ks][t][n] over K-slice of 128 --------
__global__ __launch_bounds__(256) void xproj_k(
    const ushort* __restrict__ A,      // xs16 [NT][DI]
    const ushort* __restrict__ WT,     // xp_wT [128][DI]
    float* __restrict__ P)             // dblP [KS][NT][128]
{
  __shared__ ushort As[128*32];
  __shared__ ushort Bs[128*32];
  int tid = threadIdx.x;
  int wid = tid >> 6, lane = tid & 63;
  int wr = wid >> 1, wc = wid & 1;
  int m0 = blockIdx.y*128;
  int ks = blockIdx.x;
  int lr = lane & 15, kq = lane >> 4;
  f32x4 acc[4][4] = {};
  for (int k0 = ks*128; k0 < ks*128 + 128; k0 += 32) {
    #pragma unroll
    for (int it = 0; it < 2; it++) {
      int idx = tid + it*256;
      int row = idx >> 2, seg = idx & 3;
      uint4 va = *reinterpret_cast<const uint4*>(A + (long)(m0+row)*DI + k0 + seg*8);
      uint4 vb = *reinterpret_cast<const uint4*>(WT + (long)row*DI + k0 + seg*8);
      int off = (row*64 + seg*16) ^ ((row&7)<<4);
      *reinterpret_cast<uint4*>((char*)As + off) = va;
      *reinterpret_cast<uint4*>((char*)Bs + off) = vb;
    }
    __syncthreads();
    bf16x8 af[4], bg[4];
    #pragma unroll
    for (int i = 0; i < 4; i++) {
      int row = wr*64 + i*16 + lr;
      af[i] = *reinterpret_cast<const bf16x8*>((char*)As + ((row*64 + kq*16) ^ ((row&7)<<4)));
      int col = wc*64 + i*16 + lr;
      bg[i] = *reinterpret_cast<const bf16x8*>((char*)Bs + ((col*64 + kq*16) ^ ((col&7)<<4)));
    }
    #pragma unroll
    for (int i = 0; i < 4; i++)
      #pragma unroll
      for (int j = 0; j < 4; j++)
        acc[i][j] = __builtin_amdgcn_mfma_f32_16x16x32_bf16(af[i], bg[j], acc[i][j], 0, 0, 0);
    __syncthreads();
  }
  float* C = P + (long)ks*NT*128;
  #pragma unroll
  for (int i = 0; i < 4; i++)
    #pragma unroll
    for (int j = 0; j < 4; j++)
      #pragma unroll
      for (int r = 0; r < 4; r++) {
        int m = m0 + wr*64 + i*16 + kq*4 + r;
        int n = wc*64 + j*16 + lr;
        C[(long)m*128 + n] = acc[i][j][r];
      }
}

// -------- reduce KS partials + transpose -> dblT[128][NT] --------
__global__ __launch_bounds__(256) void dblred_k(
    const float* __restrict__ P, float* __restrict__ dblT)
{
  __shared__ float t[32][33];
  int t0 = blockIdx.x*32, n0 = blockIdx.y*32;
  int tx = threadIdx.x & 31, ty = threadIdx.x >> 5;
  #pragma unroll
  for (int i = 0; i < 4; i++) {
    float s = 0.f;
    long o = (long)(t0+ty+8*i)*128 + n0+tx;
    #pragma unroll
    for (int sl = 0; sl < KS; sl++) s += P[(long)sl*NT*128 + o];
    t[ty+8*i][tx] = s;
  }
  __syncthreads();
  #pragma unroll
  for (int i = 0; i < 4; i++)
    dblT[(long)(n0+ty+8*i)*NT + t0+tx] = t[tx][ty+8*i];
}

// -------- dt_proj fused: deltaT[d][t] = softplus(dt_wT[d][:] @ dblT[:64][t] + b[d]) --------
__global__ __launch_bounds__(256) void dtg_k(
    const float* __restrict__ dblT, const ushort* __restrict__ dtw,
    const float* __restrict__ bias, float* __restrict__ deltaT)
{
  __shared__ ushort Asub[64*72];   // [d][k] padded
  __shared__ float Bsub[64*65];    // [k][t] padded
  int tid = threadIdx.x;
  int d0 = blockIdx.y*64, t0 = blockIdx.x*64;
  {
    int row = tid >> 2, seg = tid & 3;
    const uint4* src = reinterpret_cast<const uint4*>(dtw + (long)(d0+row)*64 + seg*16);
    uint4* dst = reinterpret_cast<uint4*>(Asub + row*72 + seg*16);
    dst[0] = src[0]; dst[1] = src[1];
  }
  {
    int row = tid >> 2, seg = tid & 3;
    const float4* src = reinterpret_cast<const float4*>(dblT + (long)row*NT + t0 + seg*16);
    float* dst = Bsub + row*65 + seg*16;
    #pragma unroll
    for (int q = 0; q < 4; q++) {
      float4 v = src[q];
      dst[q*4+0]=v.x; dst[q*4+1]=v.y; dst[q*4+2]=v.z; dst[q*4+3]=v.w;
    }
  }
  __syncthreads();
  int wid = tid >> 6, lane = tid & 63, lr = lane & 15, kq = lane >> 4;
  f32x4 acc[4] = {};
  #pragma unroll
  for (int kstep = 0; kstep < 2; kstep++) {
    bf16x8 af = *reinterpret_cast<const bf16x8*>(Asub + (wid*16+lr)*72 + kstep*32 + kq*8);
    #pragma unroll
    for (int j = 0; j < 4; j++) {
      bf16x8 bg;
      #pragma unroll
      for (int e = 0; e < 8; e++)
        bg[e] = (short)f2b(Bsub[(kstep*32 + kq*8 + e)*65 + j*16 + lr]);
      acc[j] = __builtin_amdgcn_mfma_f32_16x16x32_bf16(af, bg, acc[j], 0, 0, 0);
    }
  }
  #pragma unroll
  for (int j = 0; j < 4; j++)
    #pragma unroll
    for (int r = 0; r < 4; r++) {
      int d = d0 + wid*16 + kq*4 + r;
      float v = acc[j][r] + bias[d];
      v = fmaxf(v, 0.f) + log1pf(__expf(-fabsf(v)));
      deltaT[(long)d*NT + t0 + j*16 + lr] = v;
    }
}

// -------- tiled causal dwconv(k=4) + silu: writes xs16 (t-major) + xsT (d-major) --------
__global__ __launch_bounds__(256) void ssm_conv2_k(
    const float* __restrict__ xz, const float* __restrict__ w4,
    const float* __restrict__ bias, ushort* __restrict__ xs16,
    float* __restrict__ xsT)
{
  __shared__ float tile[64][65];
  int d0 = blockIdx.x*64, t0 = blockIdx.y*64;
  int wv = threadIdx.x >> 6, lane = threadIdx.x & 63;
  int d = d0 + lane;
  float w0 = w4[d*4+0], w1 = w4[d*4+1], w2 = w4[d*4+2], w3 = w4[d*4+3];
  float bs = bias[d];
  int tstart = t0 + wv*16;
  int lstart = tstart & (LL-1);
  const float* xp = xz + (long)tstart*2*DI + d;
  float x0 = (lstart >= 3) ? xp[-3*2*DI] : 0.f;
  float x1 = (lstart >= 2) ? xp[-2*2*DI] : 0.f;
  float x2 = (lstart >= 1) ? xp[-1*2*DI] : 0.f;
  #pragma unroll
  for (int i = 0; i < 16; i++) {
    float x3 = xp[(long)i*2*DI];
    float s = bs + w0*x0 + w1*x1 + w2*x2 + w3*x3;
    tile[wv*16+i][lane] = siluf_(s);
    x0 = x1; x1 = x2; x2 = x3;
  }
  __syncthreads();
  #pragma unroll
  for (int i = 0; i < 16; i++) {
    int tt = wv + i*4;
    xs16[(long)(t0+tt)*DI + d0 + lane] = f2b(tile[tt][lane]);
  }
  #pragma unroll
  for (int i = 0; i < 16; i++) {
    int dd = wv + i*4;
    xsT[(long)(d0+dd)*NT + t0 + lane] = tile[lane][dd];
  }
}

// ======== chunked selective scan ========
// merged local scan: from h=0, writes y0 (ygT), hend, sumdt in ONE pass.
// 256 threads = 4 waves; each wave owns one (channel-pair, chunk).
// Per half-wave private LDS 32x32 (stagger addressing, no pad, no barriers).
__global__ __launch_bounds__(256) void scanA_k(
  const float* __restrict__ deltaT, const float* __restrict__ xsT,
  const float* __restrict__ dblT, const float* __restrict__ A_log,
  float* __restrict__ ygT, float* __restrict__ hend, float* __restrict__ sumdt)
{
  __shared__ float ys[8*1024];
  int tid = threadIdx.x;
  int wid = tid >> 6, lane = tid & 63, half = lane >> 5, ln = lane & 31;
  int bi = blockIdx.x*4 + wid;       // 0..16383
  int pair = bi >> 4, c = bi & (NC-1);
  int ch = pair*2 + half;
  int b = ch >> 10, d = ch & (DI-1);
  float An = -__expf(A_log[d*DS + ln]);
  long base = (long)b*LL + c*CL;
  const float* dtp = deltaT + (long)d*NT + base;
  const float* xsp = xsT + (long)d*NT + base;
  const float4* Bp = reinterpret_cast<const float4*>(dblT + (long)(64+ln)*NT + base);
  const float4* Cp = reinterpret_cast<const float4*>(dblT + (long)(96+ln)*NT + base);
  float* yp = ygT + (long)d*NT + base;
  float* lds = ys + (wid*2 + half)*1024;
  float h = 0.f, sdt = 0.f;
  for (int g = 0; g < CL/32; g++) {
    float dtv  = dtp[g*32 + ln];
    float dtuv = dtv * xsp[g*32 + ln];
    float Bv[32], Cv[32];
    #pragma unroll
    for (int q = 0; q < 8; q++) {
      float4 v = Bp[g*8+q];
      Bv[q*4+0]=v.x; Bv[q*4+1]=v.y; Bv[q*4+2]=v.z; Bv[q*4+3]=v.w;
      float4 u = Cp[g*8+q];
      Cv[q*4+0]=u.x; Cv[q*4+1]=u.y; Cv[q*4+2]=u.z; Cv[q*4+3]=u.w;
    }
    float s = dtv;
    #pragma unroll
    for (int off = 16; off >= 1; off >>= 1) s += __shfl_xor(s, off, 32);
    sdt += s;
    // stage dt/dtu in rows 30,31 (overwritten only by the LAST chain sub-block)
    lds[960 + ln] = dtv;
    lds[992 + ln] = dtuv;
    // 4 sub-blocks of 8 t: broadcast-read stage, materialize av/wv, then pure FMA chain
    #pragma unroll
    for (int sub = 0; sub < 4; sub++) {
      float4 a0 = *reinterpret_cast<const float4*>(&lds[960 + sub*8]);
      float4 a1 = *reinterpret_cast<const float4*>(&lds[964 + sub*8]);
      float4 u0 = *reinterpret_cast<const float4*>(&lds[992 + sub*8]);
      float4 u1 = *reinterpret_cast<const float4*>(&lds[996 + sub*8]);
      float av[8], wv[8];
      av[0]=__expf(a0.x*An); av[1]=__expf(a0.y*An); av[2]=__expf(a0.z*An); av[3]=__expf(a0.w*An);
      av[4]=__expf(a1.x*An); av[5]=__expf(a1.y*An); av[6]=__expf(a1.z*An); av[7]=__expf(a1.w*An);
      wv[0]=u0.x*Bv[sub*8+0]; wv[1]=u0.y*Bv[sub*8+1]; wv[2]=u0.z*Bv[sub*8+2]; wv[3]=u0.w*Bv[sub*8+3];
      wv[4]=u1.x*Bv[sub*8+4]; wv[5]=u1.y*Bv[sub*8+5]; wv[6]=u1.z*Bv[sub*8+6]; wv[7]=u1.w*Bv[sub*8+7];
      __builtin_amdgcn_sched_barrier(0);   // keep exp/loads off the h-chain
      #pragma unroll
      for (int k = 0; k < 8; k++) {
        int tt = sub*8 + k;
        h = fmaf(av[k], h, wv[k]);
        lds[tt*32 + ln] = h * Cv[tt];      // bank = ln, conflict-free
      }
    }
    // y reduce: staggered row read, bank = (k+ln)&31, conflict-free, no barrier
    float y = 0.f;
    #pragma unroll
    for (int k = 0; k < 32; k++) y += lds[ln*32 + ((k + ln) & 31)];
    yp[g*32 + ln] = y;
  }
  hend[((long)c*2048 + ch)*32 + ln] = h;
  if (ln == 0) sumdt[c*2048 + ch] = sdt;
}

// sequential chunk combine; hend[c] overwritten with initial state S_c
__global__ __launch_bounds__(256) void scan2_k(
  float* __restrict__ hend, const float* __restrict__ sumdt,
  const float* __restrict__ A_log)
{
  int idx = blockIdx.x*256 + threadIdx.x;   // 0..65535
  int ch = idx >> 5, n = idx & 31;
  int d = ch & (DI-1);
  float An = -__expf(A_log[d*DS + n]);
  float H = 0.f;
  for (int c = 0; c < NC; c++) {
    long o = ((long)c*2048 + ch)*32 + n;
    float he = hend[o];
    float P = __expf(An * sumdt[c*2048 + ch]);
    hend[o] = H;
    H = P*H + he;
  }
}

// h_init correction: y[d][t] += sum_n C_t[n]*exp(A_n*cumdt_t)*hini[n]
// 4 waves per block; each wave = one (channel, chunk); chunks 1..NC-1
__global__ __launch_bounds__(256) void fix_k(
  const float* __restrict__ deltaT, const float* __restrict__ dblT,
  const float* __restrict__ A_log, const float* __restrict__ hini,
  float* __restrict__ ygT)
{
  int tid = threadIdx.x;
  int wid = tid >> 6, lane = tid & 63;
  int bi = blockIdx.x*4 + wid;       // 0..30719 = 2048*(NC-1)
  int ch = bi / (NC-1);
  int c  = 1 + bi % (NC-1);
  int b = ch >> 10, d = ch & (DI-1);
  long base = (long)b*LL + c*CL;
  const float* dtp = deltaT + (long)d*NT + base;
  float pA = dtp[lane];
  float pB = dtp[64 + lane];
  // inclusive prefix over 128 t (two 64-halves)
  #pragma unroll
  for (int off = 1; off < 64; off <<= 1) {
    float ta = __shfl(pA, lane-off, 64);
    float tb = __shfl(pB, lane-off, 64);
    if (lane >= off) { pA += ta; pB += tb; }
  }
  pB += __shfl(pA, 63, 64);
  float hv   = hini[((long)c*2048 + ch)*32 + (lane & 31)];
  float Aown = -__expf(A_log[d*DS + (lane & 31)]);
  const float* Cbase = dblT + (long)96*NT + base;
  float yA = 0.f, yB = 0.f;
  #pragma unroll 8
  for (int n = 0; n < 32; n++) {
    float An = __shfl(Aown, n, 32);
    float hn = __shfl(hv, n, 32);
    const float* Cr = Cbase + (long)n*NT;
    yA = fmaf(Cr[lane]      * __expf(An*pA), hn, yA);
    yB = fmaf(Cr[64 + lane] * __expf(An*pB), hn, yB);
  }
  float* yp = ygT + (long)d*NT + base;
  yp[lane]      += yA;
  yp[64 + lane] += yB;
}

// -------- yg16[t][d] = bf16((ygT[d][t] + u*D) * silu(z)) --------
__global__ __launch_bounds__(256) void mulz_k(
    const float* __restrict__ ygT, const ushort* __restrict__ xs16,
    const float* __restrict__ xz, const float* __restrict__ Dp,
    ushort* __restrict__ yg16)
{
  __shared__ float tile[32][33];
  int d0 = blockIdx.x*32, t0 = blockIdx.y*32;
  int tx = threadIdx.x & 31, ty = threadIdx.x >> 5;
  #pragma unroll
  for (int k = 0; k < 4; k++)
    tile[ty+8*k][tx] = ygT[(long)(d0+ty+8*k)*NT + t0+tx];
  __syncthreads();
  #pragma unroll
  for (int k = 0; k < 4; k++) {
    long tok = t0+ty+8*k; int d = d0+tx;
    float u = b2f(xs16[tok*DI + d]);
    float z = xz[tok*2*DI + DI + d];
    yg16[tok*DI + d] = f2b((tile[tx][ty+8*k] + u*Dp[d]) * siluf_(z));
  }
}

// -------- combined = bf16(ssm*silu(ge) + xc*(1-gate)) --------
__global__ __launch_bounds__(256) void combine_k(
    const float* __restrict__ ssm, const float* __restrict__ gate,
    const float* __restrict__ xc, ushort* __restrict__ comb16)
{
  long i = (long)blockIdx.x*256 + threadIdx.x;
  int o = (int)(i & (DI-1));
  long tok = i >> 10;
  float gv = gate[tok*DM + (o>>1)];
  comb16[i] = f2b(ssm[i] * siluf_(gv) + xc[i] * (1.f - gv));
}

// -------- final LN over 512 of (pre + residual) --------
__global__ __launch_bounds__(256) void final_ln_k(
    const float* __restrict__ pre, const float* __restrict__ x,
    const float* __restrict__ g, const float* __restrict__ bt, float* __restrict__ out)
{
  int token = blockIdx.x;
  __shared__ float red[4];
  float v[2]; float sum = 0.f;
  #pragma unroll
  for (int i = 0; i < 2; i++) {
    int o = threadIdx.x + i*256;
    float t = pre[(long)token*DM+o] + x[(long)token*DM+o];
    v[i] = t; sum += t;
  }
  float mean = block_sum4(sum, red) * (1.f/DM);
  float vs = 0.f;
  #pragma unroll
  for (int i = 0; i < 2; i++) { float d = v[i]-mean; vs += d*d; }
  float var = block_sum4(vs, red) * (1.f/DM);
  float inv = rsqrtf(var + 1e-5f);
  #pragma unroll
  for (int i = 0; i < 2; i++) {
    int o = threadIdx.x + i*256;
    out[(long)token*DM + o] = (v[i]-mean)*inv*g[o] + bt[o];
  }
}

extern "C" void kernel_launch(void* const* d_in, const int* in_sizes, int n_in,
                              void* d_out, int out_size, void* d_ws, size_t ws_size,
                              hipStream_t stream)
{
  const float* x         = (const float*)d_in[0];
  const float* conv_w    = (const float*)d_in[1];
  const float* conv_b    = (const float*)d_in[2];
  const float* gate_w    = (const float*)d_in[3];
  const float* gate_b    = (const float*)d_in[4];
  const float* out_w     = (const float*)d_in[5];
  const float* out_b     = (const float*)d_in[6];
  const float* ln1_g     = (const float*)d_in[7];
  const float* ln1_b     = (const float*)d_in[8];
  const float* ln2_g     = (const float*)d_in[9];
  const float* ln2_b     = (const float*)d_in[10];
  const float* in_proj_w = (const float*)d_in[11];
  const float* ssm_conv_w= (const float*)d_in[12];
  const float* ssm_conv_b= (const float*)d_in[13];
  const float* x_proj_w  = (const float*)d_in[14];
  const float* dt_proj_w = (const float*)d_in[15];
  const float* dt_proj_b = (const float*)d_in[16];
  const float* A_log     = (const float*)d_in[17];
  const float* D_param   = (const float*)d_in[18];
  const float* out_proj_w= (const float*)d_in[19];

  float* ws     = (float*)d_ws;
  float* xz     = ws;                    // 8388608
  float* xc     = xz + 8388608;          // 4194304
  float* gate   = xc + 4194304;          // 2097152
  float* xsT    = gate + 2097152;        // 4194304
  float* R      = xsT + 4194304;         // 4194304 (16MB multi-use region)
  float* dblT   = R + 4194304;           // 524288
  float* deltaT = dblT + 524288;         // 4194304
  float* ygT    = deltaT + 4194304;      // 4194304

  // R region aliases (lifetimes disjoint):
  ushort* x16   = (ushort*)R;            // steps 1-4   (2097152 ush)
  ushort* xc16  = x16 + 2097152;         // steps 3-5   (4194304 ush)
  float*  dblP  = R;                     // steps 7-8   (KS*NT*128 = 4194304 f32)
  float*  hend  = R;                     // steps 10-12 (1048576 f32)
  float*  ssm   = R;                     // steps 14-15 (4194304 f32)
  float*  pre   = deltaT;                // steps 16-17 (deltaT dead after fix)

  ushort* b16   = (ushort*)(ygT + 4194304);
  ushort* yg16  = b16;                   // 4194304 ush
  ushort* xs16  = yg16 + 4194304;        // 4194304 ush
  ushort* comb16= xs16;                  // reuse after mulz
  ushort* gate_wT = xs16 + 4194304;      // 262144
  ushort* in_wT   = gate_wT + 262144;    // 2097152
  ushort* xp_wT   = in_wT + 2097152;     // 131072
  ushort* dt_wT   = xp_wT + 131072;      // 65536
  ushort* op_wT   = dt_wT + 65536;       // 1048576
  ushort* ow_wT   = op_wT + 1048576;     // 524288
  float*  sumdt   = (float*)(ow_wT + 524288);  // 32768 f32
  float* outp   = (float*)d_out;

  convx_k<<<(NT*DM/4)/256, 256, 0, stream>>>(x, x16);                                      // 1
  wtall_k<<<4032, 256, 0, stream>>>(gate_w, in_proj_w, x_proj_w, dt_proj_w, out_proj_w, out_w,
                                    gate_wT, in_wT, xp_wT, dt_wT, op_wT, ow_wT);           // 2
  conv_ln_k<<<NT, 256, 0, stream>>>(x, conv_w, conv_b, ln2_g, ln2_b, xc, xc16);            // 3
  bgemm_k<<<dim3(DM/128, NT/128), 256, 0, stream>>>(x16, DM, gate_wT, gate_b, gate, NT, DM, DM, 1);       // 4
  bgemm_k<<<dim3(2*DI/128, NT/128), 256, 0, stream>>>(xc16, DI, in_wT, nullptr, xz, NT, 2*DI, DI, 0);     // 5
  ssm_conv2_k<<<dim3(DI/64, NT/64), 256, 0, stream>>>(xz, ssm_conv_w, ssm_conv_b, xs16, xsT);             // 6
  xproj_k<<<dim3(KS, NT/128), 256, 0, stream>>>(xs16, xp_wT, dblP);                        // 7
  dblred_k<<<dim3(NT/32, 128/32), 256, 0, stream>>>(dblP, dblT);                           // 8
  dtg_k<<<dim3(NT/64, DI/64), 256, 0, stream>>>(dblT, dt_wT, dt_proj_b, deltaT);           // 9
  scanA_k<<<4096, 256, 0, stream>>>(deltaT, xsT, dblT, A_log, ygT, hend, sumdt);           // 10
  scan2_k<<<(2048*32)/256, 256, 0, stream>>>(hend, sumdt, A_log);                          // 11
  fix_k<<<2048*(NC-1)/4, 256, 0, stream>>>(deltaT, dblT, A_log, hend, ygT);                // 12
  mulz_k<<<dim3(DI/32, NT/32), 256, 0, stream>>>(ygT, xs16, xz, D_param, yg16);            // 13
  bgemm_k<<<dim3(DI/128, NT/128), 256, 0, stream>>>(yg16, DI, op_wT, nullptr, ssm, NT, DI, DI, 0);        // 14
  combine_k<<<(NT*DI)/256, 256, 0, stream>>>(ssm, gate, xc, comb16);                       // 15
  bgemm_k<<<dim3(DM/128, NT/128), 256, 0, stream>>>(comb16, DI, ow_wT, out_b, pre, NT, DM, DI, 3);        // 16
  final_ln_k<<<NT, 256, 0, stream>>>(pre, x, ln1_g, ln1_b, outp);                          // 17
}